// Round 6
// baseline (8122.977 us; speedup 1.0000x reference)
//
#include <hip/hip_runtime.h>

// ---- static config ----
static constexpr int NN   = 128;   // dialogues
static constexpr int LL   = 64;    // utterance length
static constexpr int KWIN = 40;
static constexpr int KEFF = 40;
static constexpr int NQ   = 127;   // N-1
static constexpr int NCLS = 6;
static constexpr int KP   = 320;   // padded K for MFMA GEMMs (300 -> 320)

// scan residency split: 57 GRU groups = 14 LDS + 24 VGPR + 19 streamed
// att: 38 groups = 14 LDS + 24 VGPR + 0 streamed
static constexpr int GRU_LDS_G = 14;
static constexpr size_t SCAN_LDS_BYTES = 143360;

typedef __attribute__((ext_vector_type(8))) short short8;
typedef __attribute__((ext_vector_type(4))) float floatx4;

__device__ __forceinline__ float sigm(float x) { return 1.f / (1.f + __expf(-x)); }
__device__ __forceinline__ short f2bf(float f) {
    unsigned x = __float_as_uint(f);
    unsigned r = (x + 0x7fffu + ((x >> 16) & 1u)) >> 16;
    return (short)r;
}
__device__ __forceinline__ void bfp(unsigned v, float& lo, float& hi) {
    lo = __uint_as_float(v << 16);
    hi = __uint_as_float(v & 0xffff0000u);
}
__device__ __forceinline__ void dot8(uint4 wv, float4 h0, float4 h1, float& acc) {
    float l0, u0, l1, u1, l2, u2, l3, u3;
    bfp(wv.x, l0, u0); bfp(wv.y, l1, u1);
    bfp(wv.z, l2, u2); bfp(wv.w, l3, u3);
    acc = fmaf(l0, h0.x, acc); acc = fmaf(u0, h0.y, acc);
    acc = fmaf(l1, h0.z, acc); acc = fmaf(u1, h0.w, acc);
    acc = fmaf(l2, h1.x, acc); acc = fmaf(u2, h1.y, acc);
    acc = fmaf(l3, h1.z, acc); acc = fmaf(u3, h1.w, acc);
}

// ---------------------------------------------------------------------------
// Gather + convert: A[r=t*128+n][0..319] = bf16(emb[ids[n*64+t]]), zero-pad
// ---------------------------------------------------------------------------
__global__ void k_gather_bf16(const float* __restrict__ emb,
                              const int* __restrict__ ids,
                              short* __restrict__ A)
{
    int r = blockIdx.x;            // t*128 + n
    int n = r & (NN - 1);
    int t = r >> 7;
    int id = ids[n * LL + t];
    int e = threadIdx.x;           // 320 threads
    float v = (e < 300) ? emb[(size_t)id * 300 + e] : 0.f;
    A[(size_t)r * KP + e] = f2bf(v);
}

// f32 [rows][300] -> bf16 [rows][320], zero pad (GEMM operands)
__global__ void k_conv320(const float* __restrict__ src, short* __restrict__ dst)
{
    int r = blockIdx.x, e = threadIdx.x;   // 320 threads
    float v = (e < 300) ? src[(size_t)r * 300 + e] : 0.f;
    dst[(size_t)r * KP + e] = f2bf(v);
}

// ---------------------------------------------------------------------------
// Pack GRU Whh [2][900][300] -> [2][57][600][8sh]
// group g = cs*3+s (cs in [0,19), s in [0,3)); thread u = p*300+j
// entry = bf16 of W[d][s*300+j][152p + 8cs + i], zero beyond col 299
// ---------------------------------------------------------------------------
__global__ void k_pack_gru600(const float* __restrict__ W, short* __restrict__ dst)
{
    int idx = blockIdx.x * 256 + threadIdx.x;     // 2*57*600 = 68400
    if (idx >= 2 * 57 * 600) return;
    int u = idx % 600, gc = idx / 600;
    int g = gc % 57, d = gc / 57;
    int cs = g / 3, s = g - cs * 3;
    int p = u / 300, j = u - p * 300;
    const float* src = W + ((size_t)d * 900 + s * 300 + j) * 300;
    int cb = 152 * p + 8 * cs;
    short8 sv;
#pragma unroll
    for (int i = 0; i < 8; ++i) {
        int c = cb + i;
        sv[i] = (c < 300) ? f2bf(src[c]) : (short)0;
    }
    *(short8*)(dst + ((size_t)(d * 57 + g) * 600 + u) * 8) = sv;
}

// ---------------------------------------------------------------------------
// Pack attn Ur/Uw [6][300][300] -> [6][38][600][8sh]
// group g = cs*2+s (s=0:Ur, 1:Uw); thread u = p*300+m; cols 152p+8cs..+8
// ---------------------------------------------------------------------------
__global__ void k_pack_att600(const float* __restrict__ Ur, const float* __restrict__ Uw,
                              short* __restrict__ dst)
{
    int idx = blockIdx.x * 256 + threadIdx.x;     // 6*38*600 = 136800
    if (idx >= 6 * 38 * 600) return;
    int u = idx % 600, gc = idx / 600;
    int g = gc % 38, hd = gc / 38;
    int cs = g >> 1, s = g & 1;
    int p = u / 300, m = u - p * 300;
    const float* src = (s ? Uw : Ur) + ((size_t)hd * 300 + m) * 300;
    int cb = 152 * p + 8 * cs;
    short8 sv;
#pragma unroll
    for (int i = 0; i < 8; ++i) {
        int c = cb + i;
        sv[i] = (c < 300) ? f2bf(src[c]) : (short)0;
    }
    *(short8*)(dst + ((size_t)(hd * 38 + g) * 600 + u) * 8) = sv;
}

// ---------------------------------------------------------------------------
// bf16 MFMA GEMM (B^T layout): C[r,c] = sum_k A[r,k]*B[c,k] + bias[c], f32 out
// ---------------------------------------------------------------------------
__global__ __launch_bounds__(256)
void k_mgemm(const short* __restrict__ A, const short* __restrict__ B,
             const float* __restrict__ bias, float* __restrict__ C,
             int R, int Cc)
{
    __shared__ short As[128 * 40];
    __shared__ short Bs[128 * 40];
    const int tid = threadIdx.x;
    const int r0 = blockIdx.y * 128, c0 = blockIdx.x * 128;
    const int w = tid >> 6, lane = tid & 63;
    const int m16 = lane & 15, quad = lane >> 4;
    const int wm = w & 1, wn = w >> 1;
    floatx4 acc[4][4];
#pragma unroll
    for (int i = 0; i < 4; ++i)
#pragma unroll
        for (int j = 0; j < 4; ++j) acc[i][j] = (floatx4){0.f, 0.f, 0.f, 0.f};

    const int ra0 = tid >> 2,         sa0 = tid & 3;
    const int ra1 = (tid + 256) >> 2, sa1 = tid & 3;

    for (int k0 = 0; k0 < KP; k0 += 32) {
        short8 za = {0,0,0,0,0,0,0,0};
        short8 a0 = za, a1 = za, b0 = za, b1 = za;
        if (r0 + ra0 < R) a0 = *(const short8*)(A + (size_t)(r0 + ra0) * KP + k0 + sa0 * 8);
        if (r0 + ra1 < R) a1 = *(const short8*)(A + (size_t)(r0 + ra1) * KP + k0 + sa1 * 8);
        if (c0 + ra0 < Cc) b0 = *(const short8*)(B + (size_t)(c0 + ra0) * KP + k0 + sa0 * 8);
        if (c0 + ra1 < Cc) b1 = *(const short8*)(B + (size_t)(c0 + ra1) * KP + k0 + sa1 * 8);
        *(short8*)(As + ra0 * 40 + sa0 * 8) = a0;
        *(short8*)(As + ra1 * 40 + sa1 * 8) = a1;
        *(short8*)(Bs + ra0 * 40 + sa0 * 8) = b0;
        *(short8*)(Bs + ra1 * 40 + sa1 * 8) = b1;
        __syncthreads();
        short8 af[4], bfr[4];
#pragma unroll
        for (int mt = 0; mt < 4; ++mt)
            af[mt] = *(const short8*)(As + (wm * 64 + mt * 16 + m16) * 40 + quad * 8);
#pragma unroll
        for (int nt = 0; nt < 4; ++nt)
            bfr[nt] = *(const short8*)(Bs + (wn * 64 + nt * 16 + m16) * 40 + quad * 8);
#pragma unroll
        for (int mt = 0; mt < 4; ++mt)
#pragma unroll
            for (int nt = 0; nt < 4; ++nt)
                acc[mt][nt] = __builtin_amdgcn_mfma_f32_16x16x32_bf16(
                    af[mt], bfr[nt], acc[mt][nt], 0, 0, 0);
        __syncthreads();
    }
#pragma unroll
    for (int mt = 0; mt < 4; ++mt) {
#pragma unroll
        for (int nt = 0; nt < 4; ++nt) {
            int col = c0 + wn * 64 + nt * 16 + m16;
            if (col >= Cc) continue;
            float bv = bias ? bias[col] : 0.f;
#pragma unroll
            for (int i = 0; i < 4; ++i) {
                int row = r0 + wm * 64 + mt * 16 + quad * 4 + i;
                if (row < R) C[(size_t)row * Cc + col] = acc[mt][nt][i] + bv;
            }
        }
    }
}

// ---------------------------------------------------------------------------
// f32 GEMM (small lin layer): C = act(A @ B^T + bias)
// ---------------------------------------------------------------------------
__global__ __launch_bounds__(256)
void k_gemm(const float* __restrict__ A, const float* __restrict__ B,
            const float* __restrict__ bias, float* __restrict__ C,
            int R, int Cc, int K, int actTanh)
{
    __shared__ __align__(16) float Asm[16][132];
    __shared__ __align__(16) float Bsm[16][132];
    const int tid = threadIdx.x;
    const int r0 = blockIdx.y * 128, c0 = blockIdx.x * 128;
    const int li = tid >> 1, lk = (tid & 1) * 8;
    const int tx = tid & 15, ty = tid >> 4;
    float acc[8][8];
#pragma unroll
    for (int i = 0; i < 8; ++i)
#pragma unroll
        for (int j = 0; j < 8; ++j) acc[i][j] = 0.f;
    const int nch = (K + 15) >> 4;
    for (int ch = 0; ch < nch; ++ch) {
        const int k0 = ch * 16;
        {
            float v[8];
            int gr = r0 + li, kb = k0 + lk;
            if (gr < R && kb + 8 <= K) {
                const float* p = A + (size_t)gr * K + kb;
                *(float4*)&v[0] = *(const float4*)p;
                *(float4*)&v[4] = *(const float4*)(p + 4);
            } else {
#pragma unroll
                for (int z = 0; z < 8; ++z) {
                    int k = kb + z;
                    v[z] = (gr < R && k < K) ? A[(size_t)gr * K + k] : 0.f;
                }
            }
#pragma unroll
            for (int z = 0; z < 8; ++z) Asm[lk + z][li] = v[z];
        }
        {
            float v[8];
            int gr = c0 + li, kb = k0 + lk;
            if (gr < Cc && kb + 8 <= K) {
                const float* p = B + (size_t)gr * K + kb;
                *(float4*)&v[0] = *(const float4*)p;
                *(float4*)&v[4] = *(const float4*)(p + 4);
            } else {
#pragma unroll
                for (int z = 0; z < 8; ++z) {
                    int k = kb + z;
                    v[z] = (gr < Cc && k < K) ? B[(size_t)gr * K + k] : 0.f;
                }
            }
#pragma unroll
            for (int z = 0; z < 8; ++z) Bsm[lk + z][li] = v[z];
        }
        __syncthreads();
#pragma unroll
        for (int kk = 0; kk < 16; ++kk) {
            float a[8], b[8];
            *(float4*)&a[0] = *(const float4*)&Asm[kk][ty * 8];
            *(float4*)&a[4] = *(const float4*)&Asm[kk][ty * 8 + 4];
            *(float4*)&b[0] = *(const float4*)&Bsm[kk][tx * 8];
            *(float4*)&b[4] = *(const float4*)&Bsm[kk][tx * 8 + 4];
#pragma unroll
            for (int i = 0; i < 8; ++i)
#pragma unroll
                for (int j = 0; j < 8; ++j) acc[i][j] = fmaf(a[i], b[j], acc[i][j]);
        }
        __syncthreads();
    }
#pragma unroll
    for (int i = 0; i < 8; ++i) {
        int r = r0 + ty * 8 + i;
        if (r >= R) continue;
#pragma unroll
        for (int j = 0; j < 8; ++j) {
            int c = c0 + tx * 8 + j;
            if (c >= Cc) continue;
            float v = acc[i][j];
            if (bias) v += bias[c];
            if (actTanh) v = tanhf(v);
            C[(size_t)r * Cc + c] = v;
        }
    }
}

// ---------------------------------------------------------------------------
// GRU scan core: 600 threads, thread (p,j) owns 3 gate-rows over cols
// [152p,152p+152). Weights: 14 groups LDS-resident, 24 in VGPRs, 19 streamed
// (s=0 of each cs) with depth-4 rolling prefetch. h broadcast from LDS.
// ---------------------------------------------------------------------------
template<bool IS_UTT>
__device__ __forceinline__ void gru_scan_body(
    const short* __restrict__ Wp,   // [2][57][600][8sh]
    const float* __restrict__ bhh,
    const float* __restrict__ gi,   // [T*NB][1800]
    int d, int chain, int NB, int len,
    float* __restrict__ outp)       // maxpool row (utt) or hout base (ctx)
{
    extern __shared__ char smem[];
    short* wlds = (short*)smem;                              // [14][600][8]
    float* hs   = (float*)(smem + GRU_LDS_G * 600 * 16);     // [304]
    float* pds  = hs + 304;                                  // [3][2][304]
    const int tid = threadIdx.x;
    const int p = tid / 300, j = tid - p * 300;
    const uint4* wall = (const uint4*)(Wp + (size_t)d * 57 * 600 * 8);
    // VGPR-resident: s=2 all cs (19) + s=1 cs 14..18 (5)
    uint4 wv2[19], wv1[5];
#pragma unroll
    for (int cs = 0; cs < 19; ++cs) wv2[cs] = wall[(size_t)(cs * 3 + 2) * 600 + tid];
#pragma unroll
    for (int cs = 14; cs < 19; ++cs) wv1[cs - 14] = wall[(size_t)(cs * 3 + 1) * 600 + tid];
    // LDS-resident: s=1 cs 0..13
#pragma unroll
    for (int cs = 0; cs < GRU_LDS_G; ++cs)
        *(uint4*)(wlds + ((size_t)cs * 600 + tid) * 8) = wall[(size_t)(cs * 3 + 1) * 600 + tid];
    if (tid < 304) hs[tid] = 0.f;
    float br = 0.f, bz = 0.f, bn = 0.f;
    if (tid < 300) {
        br = bhh[d * 900 + tid];
        bz = bhh[d * 900 + 300 + tid];
        bn = bhh[d * 900 + 600 + tid];
    }
    float mx = -1e30f;
    __syncthreads();
    for (int t = 0; t < len; ++t) {
        int ts = d ? (len - 1 - t) : t;
        float g0 = 0.f, g1 = 0.f, g2 = 0.f;
        if (tid < 300) {   // prefetch gate inputs (used after the barrier)
            size_t row = ((size_t)(ts * NB + chain)) * 1800 + d * 900 + tid;
            g0 = gi[row]; g1 = gi[row + 300]; g2 = gi[row + 600];
        }
        float a0 = 0.f, a1 = 0.f, a2 = 0.f;
        uint4 ring[4];
#pragma unroll
        for (int i = 0; i < 4; ++i) ring[i] = wall[(size_t)(i * 3) * 600 + tid];
        const int hb = 152 * p;
#pragma unroll
        for (int cs = 0; cs < 19; ++cs) {
            float4 h0 = *(const float4*)&hs[hb + 8 * cs];
            float4 h1 = *(const float4*)&hs[hb + 8 * cs + 4];
            uint4 w0 = ring[cs & 3];
            if (cs + 4 < 19) ring[cs & 3] = wall[(size_t)((cs + 4) * 3) * 600 + tid];
            dot8(w0, h0, h1, a0);
            if (cs < GRU_LDS_G) {
                uint4 wl = *(const uint4*)(wlds + ((size_t)cs * 600 + tid) * 8);
                dot8(wl, h0, h1, a1);
            } else {
                dot8(wv1[cs - GRU_LDS_G], h0, h1, a1);
            }
            dot8(wv2[cs], h0, h1, a2);
        }
        pds[(0 * 2 + p) * 304 + j] = a0;
        pds[(1 * 2 + p) * 304 + j] = a1;
        pds[(2 * 2 + p) * 304 + j] = a2;
        __syncthreads();
        if (tid < 300) {
            float dr = pds[tid] + pds[304 + tid] + br;
            float dz = pds[608 + tid] + pds[912 + tid] + bz;
            float dn = pds[1216 + tid] + pds[1520 + tid] + bn;
            float r = sigm(g0 + dr);
            float z = sigm(g1 + dz);
            float nv = tanhf(g2 + r * dn);
            float hv = (1.f - z) * nv + z * hs[tid];
            hs[tid] = hv;
            if (IS_UTT) mx = fmaxf(mx, hv);
            else outp[(size_t)ts * 300 + tid] = hv;
        }
        __syncthreads();
    }
    if (IS_UTT && tid < 300) {
        if (len < LL) mx = fmaxf(mx, 0.f);   // padded steps contribute 0
        outp[tid] = mx;
    }
}

__global__ __launch_bounds__(600, 3)
void k_utt_scan(const short* __restrict__ Wp, const float* __restrict__ bhh,
                const float* __restrict__ gi, const int* __restrict__ lens,
                float* __restrict__ maxpool)
{
    const int d = blockIdx.y, n = blockIdx.x;
    gru_scan_body<true>(Wp, bhh, gi, d, n, NN, lens[n],
                        maxpool + (size_t)n * 600 + d * 300);
}

__global__ __launch_bounds__(600, 3)
void k_ctx_scan(const short* __restrict__ Wp, const float* __restrict__ bhh,
                const float* __restrict__ gi, float* __restrict__ hout)
{
    const int d = blockIdx.y, q = blockIdx.x;
    gru_scan_body<false>(Wp, bhh, gi, d, q, NQ, KEFF,
                         hout + (((size_t)d * NQ + q) * KEFF) * 300);
}

// ---------------------------------------------------------------------------
__global__ void k_init_query(const float* __restrict__ u, float* __restrict__ query)
{
    int q = blockIdx.x;
    for (int e = threadIdx.x; e < 300; e += blockDim.x)
        query[(size_t)q * 300 + e] = u[(size_t)(q + 1) * 300 + e];
}

// ctx rows -> bf16 [5080][320] padded
__global__ void k_build_ctxA(const float* __restrict__ u, short* __restrict__ Actx)
{
    int rkq = blockIdx.x;            // k*127 + q
    int k = rkq / NQ, q = rkq - k * NQ;
    int src = q + 1 - KWIN + k;
    int e = threadIdx.x;             // 320 threads
    float v = (e < 300 && src >= 0) ? u[(size_t)src * 300 + e] : 0.f;
    Actx[(size_t)rkq * KP + e] = f2bf(v);
}

// ---------------------------------------------------------------------------
__global__ void k_combine(const float* __restrict__ u, const float* __restrict__ hout,
                          float* __restrict__ mem_bank, short* __restrict__ mrkq)
{
    int rkq = blockIdx.x;            // k*127 + q
    int k = rkq / NQ, q = rkq - k * NQ;
    int src = q + 1 - KWIN + k;
    int e = threadIdx.x;             // 320 threads
    float v = 0.f;
    if (e < 300) {
        float c = (src >= 0) ? u[(size_t)src * 300 + e] : 0.f;
        v = c + hout[((size_t)q * KEFF + k) * 300 + e]
              + hout[(((size_t)NQ + q) * KEFF + k) * 300 + e];
        mem_bank[((size_t)q * KEFF + k) * 300 + e] = v;
    }
    mrkq[(size_t)rkq * KP + e] = f2bf(v);
}

// ---------------------------------------------------------------------------
// AttnGRU scan with fused score/softmax. 600 threads; thread (p,m) owns rows
// {Ur_m, Uw_m} over cols [152p,152p+152). Weights fully resident:
// 14 groups LDS (s=0, cs<14) + 24 groups VGPR (s=0 cs 14..18, s=1 all).
// ---------------------------------------------------------------------------
__global__ __launch_bounds__(600, 3)
void k_att_scan(const short* __restrict__ Wp,     // [6][38][600][8sh]
                const float* __restrict__ burb,   // [6*300]
                const float* __restrict__ bub,    // [6*300]
                const float* __restrict__ xgr,    // [5080][1800] f32
                const float* __restrict__ xgw,
                const float* __restrict__ query,  // [127][300]
                const float* __restrict__ membank,// [127][40][300]
                float* __restrict__ hbuf,         // [2][127][300]
                int hop)
{
    extern __shared__ char smem[];
    short* wlds  = (short*)smem;                             // [14][600][8]
    float* hs    = (float*)(smem + GRU_LDS_G * 600 * 16);    // [304]
    float* pds   = hs + 304;                                 // [2][2][304]
    float* qv    = pds + 1216;                               // [304]
    float* gates = qv + 304;                                 // [40]
    float* scr   = gates + 40;                               // [40]
    const int d = blockIdx.y, q = blockIdx.x, tid = threadIdx.x;
    const int hd = hop * 2 + d;
    const int p = tid / 300, m = tid - p * 300;
    const uint4* wall = (const uint4*)(Wp + (size_t)hd * 38 * 600 * 8);
    uint4 av1[19], av0[5];
#pragma unroll
    for (int cs = 0; cs < 19; ++cs) av1[cs] = wall[(size_t)(cs * 2 + 1) * 600 + tid];
#pragma unroll
    for (int cs = 14; cs < 19; ++cs) av0[cs - 14] = wall[(size_t)(cs * 2) * 600 + tid];
#pragma unroll
    for (int cs = 0; cs < GRU_LDS_G; ++cs)
        *(uint4*)(wlds + ((size_t)cs * 600 + tid) * 8) = wall[(size_t)(cs * 2) * 600 + tid];
    if (tid < 304) {
        hs[tid] = 0.f;
        qv[tid] = (tid < 300) ? query[(size_t)q * 300 + tid] : 0.f;
    }
    float bur = 0.f, bu = 0.f;
    if (tid < 300) { bur = burb[hd * 300 + tid]; bu = bub[hd * 300 + tid]; }
    __syncthreads();
    // ---- fused scores: dot + masked softmax ----
    if (tid < 320) {
        int k = tid >> 3, part = tid & 7;
        const float* mrow = membank + ((size_t)q * KEFF + k) * 300;
        int e0 = part * 38, e1 = e0 + 38 > 300 ? 300 : e0 + 38;
        float acc = 0.f;
        for (int e = e0; e < e1; ++e) acc = fmaf(qv[e], mrow[e], acc);
        acc += __shfl_xor(acc, 1);
        acc += __shfl_xor(acc, 2);
        acc += __shfl_xor(acc, 4);
        if (part == 0) scr[k] = acc;
    }
    __syncthreads();
    if (tid < 64) {
        float s = (tid < KEFF) ? scr[tid] : -1e30f;
        if (tid < KWIN - 1 - q) s = -1e10f;     // zero-padded slots masked
        float mxs = s;
        for (int o = 32; o > 0; o >>= 1) mxs = fmaxf(mxs, __shfl_xor(mxs, o));
        float e = (tid < KEFF) ? __expf(s - mxs) : 0.f;
        float sm = e;
        for (int o = 32; o > 0; o >>= 1) sm += __shfl_xor(sm, o);
        if (tid < KEFF) gates[tid] = e / sm;
    }
    __syncthreads();
    // ---- scan ----
    for (int t = 0; t < KEFF; ++t) {
        int kq = d ? (KEFF - 1 - t) : t;
        float xr = 0.f, xw = 0.f, gt = 0.f;
        if (tid < 300) {
            size_t xi = ((size_t)(kq * NQ + q)) * 1800 + (size_t)hd * 300 + tid;
            xr = xgr[xi]; xw = xgw[xi];
            gt = gates[kq];
        }
        float a0 = 0.f, a1 = 0.f;
        const int hb = 152 * p;
#pragma unroll
        for (int cs = 0; cs < 19; ++cs) {
            float4 h0 = *(const float4*)&hs[hb + 8 * cs];
            float4 h1 = *(const float4*)&hs[hb + 8 * cs + 4];
            if (cs < GRU_LDS_G) {
                uint4 wl = *(const uint4*)(wlds + ((size_t)cs * 600 + tid) * 8);
                dot8(wl, h0, h1, a0);
            } else {
                dot8(av0[cs - GRU_LDS_G], h0, h1, a0);
            }
            dot8(av1[cs], h0, h1, a1);
        }
        pds[(0 * 2 + p) * 304 + m] = a0;
        pds[(1 * 2 + p) * 304 + m] = a1;
        __syncthreads();
        if (tid < 300) {
            float dr = pds[tid] + pds[304 + tid] + bur;
            float dw = pds[608 + tid] + pds[912 + tid] + bu;
            float r = sigm(xr + dr);
            float ht = tanhf(xw + r * dw);
            hs[tid] = gt * ht + (1.f - gt) * hs[tid];
        }
        __syncthreads();
    }
    if (tid < 300)
        hbuf[((size_t)d * NQ + q) * 300 + tid] = hs[tid];
}

__global__ void k_qupd(float* __restrict__ query, const float* __restrict__ hbuf)
{
    int q = blockIdx.x;
    for (int e = threadIdx.x; e < 300; e += blockDim.x)
        query[(size_t)q * 300 + e] += hbuf[(size_t)q * 300 + e]
                                    + hbuf[(size_t)(NQ + q) * 300 + e];
}

// ---------------------------------------------------------------------------
__global__ __launch_bounds__(64)
void k_cls(const float* __restrict__ u, const float* __restrict__ query,
           const float* __restrict__ cw, const float* __restrict__ cb,
           float* __restrict__ out)
{
    int n = blockIdx.x;
    const float* srow = (n == 0) ? u : (query + (size_t)(n - 1) * 300);
    int c = threadIdx.x & 7;
    int part = threadIdx.x >> 3;
    float p = 0.f;
    if (c < NCLS) {
        for (int e = part; e < 300; e += 8) p = fmaf(srow[e], cw[c * 300 + e], p);
    }
    p += __shfl_xor(p, 8);
    p += __shfl_xor(p, 16);
    p += __shfl_xor(p, 32);
    if (part == 0 && c < NCLS) out[n * NCLS + c] = p + cb[c];
}

// ---------------------------------------------------------------------------
extern "C" void kernel_launch(void* const* d_in, const int* in_sizes, int n_in,
                              void* d_out, int out_size, void* d_ws, size_t ws_size,
                              hipStream_t stream)
{
    const int* ids  = (const int*)d_in[0];
    const int* lens = (const int*)d_in[1];
    const float* emb   = (const float*)d_in[2];
    const float* uWih  = (const float*)d_in[3];
    const float* uWhh  = (const float*)d_in[4];
    const float* ubih  = (const float*)d_in[5];
    const float* ubhh  = (const float*)d_in[6];
    const float* linw  = (const float*)d_in[7];
    const float* linb  = (const float*)d_in[8];
    const float* cWih  = (const float*)d_in[9];
    const float* cWhh  = (const float*)d_in[10];
    const float* cbih  = (const float*)d_in[11];
    const float* cbhh  = (const float*)d_in[12];
    const float* aWr_w = (const float*)d_in[13];
    const float* aWr_b = (const float*)d_in[14];
    const float* aUr_w = (const float*)d_in[15];
    const float* aUr_b = (const float*)d_in[16];
    const float* aW_w  = (const float*)d_in[17];
    const float* aW_b  = (const float*)d_in[18];
    const float* aU_w  = (const float*)d_in[19];
    const float* aU_b  = (const float*)d_in[20];
    const float* clsw  = (const float*)d_in[21];
    const float* clsb  = (const float*)d_in[22];
    float* out = (float*)d_out;
    (void)in_sizes; (void)n_in; (void)out_size; (void)ws_size;

    // opt-in to >64KB dynamic LDS for the scan kernels (host-side, capture-safe)
    (void)hipFuncSetAttribute((const void*)k_utt_scan,
            hipFuncAttributeMaxDynamicSharedMemorySize, (int)SCAN_LDS_BYTES);
    (void)hipFuncSetAttribute((const void*)k_ctx_scan,
            hipFuncAttributeMaxDynamicSharedMemorySize, (int)SCAN_LDS_BYTES);
    (void)hipFuncSetAttribute((const void*)k_att_scan,
            hipFuncAttributeMaxDynamicSharedMemorySize, (int)SCAN_LDS_BYTES);

    char* base = (char*)d_ws;
    size_t off = 0;
    auto alloc = [&](size_t b) -> void* {
        void* r = (void*)(base + off);
        off += (b + 255) & ~(size_t)255;
        return r;
    };
    short* A_utt  = (short*)alloc((size_t)8192 * KP * 2);          //  5.2 MB
    float* giU    = (float*)alloc((size_t)8192 * 1800 * 4);        // 59.0 MB (reused: xgr)
    float* giC    = (float*)alloc((size_t)5080 * 1800 * 4);        // 36.6 MB (reused: xgw)
    short* wUihB  = (short*)alloc((size_t)1800 * KP * 2);
    short* wCihB  = (short*)alloc((size_t)1800 * KP * 2);
    short* wArB   = (short*)alloc((size_t)1800 * KP * 2);
    short* wAwB   = (short*)alloc((size_t)1800 * KP * 2);
    short* wPackU = (short*)alloc((size_t)2 * 57 * 600 * 8 * 2);   // 1.09 MB
    short* wPackC = (short*)alloc((size_t)2 * 57 * 600 * 8 * 2);
    short* wPackA = (short*)alloc((size_t)6 * 38 * 600 * 8 * 2);   // 2.19 MB
    short* Actx   = (short*)alloc((size_t)5080 * KP * 2);
    float* hout   = (float*)alloc((size_t)2 * NQ * KEFF * 300 * 4);
    float* membank= (float*)alloc((size_t)NQ * KEFF * 300 * 4);
    short* mrkq   = (short*)alloc((size_t)5080 * KP * 2);
    float* mpool  = (float*)alloc((size_t)NN * 600 * 4);
    float* uu     = (float*)alloc((size_t)NN * 300 * 4);
    float* query  = (float*)alloc((size_t)NQ * 300 * 4);
    float* hbuf   = (float*)alloc((size_t)2 * NQ * 300 * 4);
    float* xgr = giU;   // giU dead after k_utt_scan
    float* xgw = giC;   // giC dead after k_ctx_scan

    const int RKQ = NQ * KEFF;  // 5080

    // 0) weight conversions / packing
    k_conv320<<<dim3(1800), dim3(320), 0, stream>>>(uWih, wUihB);
    k_conv320<<<dim3(1800), dim3(320), 0, stream>>>(cWih, wCihB);
    k_conv320<<<dim3(1800), dim3(320), 0, stream>>>(aWr_w, wArB);
    k_conv320<<<dim3(1800), dim3(320), 0, stream>>>(aW_w, wAwB);
    k_pack_gru600<<<dim3((2 * 57 * 600 + 255) / 256), dim3(256), 0, stream>>>(uWhh, wPackU);
    k_pack_gru600<<<dim3((2 * 57 * 600 + 255) / 256), dim3(256), 0, stream>>>(cWhh, wPackC);
    k_pack_att600<<<dim3((6 * 38 * 600 + 255) / 256), dim3(256), 0, stream>>>(aUr_w, aU_w, wPackA);

    // 1) gather, 2) utt input-gate GEMM (MFMA), 3) utt scan + maxpool
    k_gather_bf16<<<dim3(LL * NN), dim3(320), 0, stream>>>(emb, ids, A_utt);
    k_mgemm<<<dim3(15, 64), dim3(256), 0, stream>>>(A_utt, wUihB, ubih, giU, 8192, 1800);
    k_utt_scan<<<dim3(NN, 2), dim3(600), SCAN_LDS_BYTES, stream>>>(wPackU, ubhh, giU, lens, mpool);
    // 4) u = tanh(maxpool @ lin_w.T + lin_b)
    k_gemm<<<dim3(3, 1), dim3(256), 0, stream>>>(mpool, linw, linb, uu, NN, 300, 600, 1);
    // 5) query init + ctx rows
    k_init_query<<<dim3(NQ), dim3(128), 0, stream>>>(uu, query);
    k_build_ctxA<<<dim3(RKQ), dim3(320), 0, stream>>>(uu, Actx);
    // 6) ctx input-gate GEMM + ctx scan + combine
    k_mgemm<<<dim3(15, 40), dim3(256), 0, stream>>>(Actx, wCihB, cbih, giC, RKQ, 1800);
    k_ctx_scan<<<dim3(NQ, 2), dim3(600), SCAN_LDS_BYTES, stream>>>(wPackC, cbhh, giC, hout);
    k_combine<<<dim3(RKQ), dim3(320), 0, stream>>>(uu, hout, membank, mrkq);
    // 7) attention x-projections (all hops/dirs)
    k_mgemm<<<dim3(15, 40), dim3(256), 0, stream>>>(mrkq, wArB, aWr_b, xgr, RKQ, 1800);
    k_mgemm<<<dim3(15, 40), dim3(256), 0, stream>>>(mrkq, wAwB, aW_b, xgw, RKQ, 1800);
    // 8) hops (scores fused into att_scan)
    for (int hop = 0; hop < 3; ++hop) {
        k_att_scan<<<dim3(NQ, 2), dim3(600), SCAN_LDS_BYTES, stream>>>(
            wPackA, aUr_b, aU_b, xgr, xgw, query, membank, hbuf, hop);
        k_qupd<<<dim3(NQ), dim3(128), 0, stream>>>(query, hbuf);
    }
    // 9) classifier
    k_cls<<<dim3(NN), dim3(64), 0, stream>>>(uu, query, clsw, clsb, out);
}

// Round 7
// 1333.589 us; speedup vs baseline: 6.0911x; 6.0911x over previous
//
#include <hip/hip_runtime.h>

// ---- static config ----
static constexpr int NN   = 128;   // dialogues
static constexpr int LL   = 64;    // utterance length
static constexpr int KWIN = 40;
static constexpr int KEFF = 40;
static constexpr int NQ   = 127;   // N-1
static constexpr int NCLS = 6;
static constexpr int KP   = 320;   // padded K for MFMA GEMMs (300 -> 320)

// GRU scans: 39 chunks = 9 LDS-resident + 30 streamed (ring depth 6)
// att scans: 40 chunks = 12 LDS-resident + 28 streamed
static constexpr int GRU_RES = 9;
static constexpr int ATT_RES = 12;
static constexpr size_t GRU_LDS = (size_t)GRU_RES * 912 * 16 + (304 + 2700) * 4;  // 143,344
static constexpr size_t ATT_LDS = (size_t)ATT_RES * 608 * 16 + (320 + 1216 + 304 + 40 + 40) * 4; // 124,416

typedef __attribute__((ext_vector_type(8))) short short8;
typedef __attribute__((ext_vector_type(4))) float floatx4;

__device__ __forceinline__ float sigm(float x) { return 1.f / (1.f + __expf(-x)); }
__device__ __forceinline__ short f2bf(float f) {
    unsigned x = __float_as_uint(f);
    unsigned r = (x + 0x7fffu + ((x >> 16) & 1u)) >> 16;
    return (short)r;
}
__device__ __forceinline__ void bfp(unsigned v, float& lo, float& hi) {
    lo = __uint_as_float(v << 16);
    hi = __uint_as_float(v & 0xffff0000u);
}
__device__ __forceinline__ void dot8(uint4 wv, float4 h0, float4 h1, float& acc) {
    float l0, u0, l1, u1, l2, u2, l3, u3;
    bfp(wv.x, l0, u0); bfp(wv.y, l1, u1);
    bfp(wv.z, l2, u2); bfp(wv.w, l3, u3);
    acc = fmaf(l0, h0.x, acc); acc = fmaf(u0, h0.y, acc);
    acc = fmaf(l1, h0.z, acc); acc = fmaf(u1, h0.w, acc);
    acc = fmaf(l2, h1.x, acc); acc = fmaf(u2, h1.y, acc);
    acc = fmaf(l3, h1.z, acc); acc = fmaf(u3, h1.w, acc);
}

// ---------------------------------------------------------------------------
// Gather + convert: A[r=t*128+n][0..319] = bf16(emb[ids[n*64+t]]), zero-pad
// ---------------------------------------------------------------------------
__global__ void k_gather_bf16(const float* __restrict__ emb,
                              const int* __restrict__ ids,
                              short* __restrict__ A)
{
    int r = blockIdx.x;            // t*128 + n
    int n = r & (NN - 1);
    int t = r >> 7;
    int id = ids[n * LL + t];
    int e = threadIdx.x;           // 320 threads
    float v = (e < 300) ? emb[(size_t)id * 300 + e] : 0.f;
    A[(size_t)r * KP + e] = f2bf(v);
}

// f32 [rows][300] -> bf16 [rows][320], zero pad (GEMM operands)
__global__ void k_conv320(const float* __restrict__ src, short* __restrict__ dst)
{
    int r = blockIdx.x, e = threadIdx.x;   // 320 threads
    float v = (e < 300) ? src[(size_t)r * 300 + e] : 0.f;
    dst[(size_t)r * KP + e] = f2bf(v);
}

// ---------------------------------------------------------------------------
// Pack GRU Whh [2][900][300] f32 -> chunk-interleaved bf16 [2][39][912][8sh]
// thread u=(p*300+m) owns rows {m, m+300, m+600} cols [100p,100p+100)
// chunk c = cs*3+s : 8 bf16 of row (s*300+m), cols 100p+8cs .. +8 (0 if >=100)
// ---------------------------------------------------------------------------
__global__ void k_pack_gru(const float* __restrict__ W, short* __restrict__ dst)
{
    int idx = blockIdx.x * 256 + threadIdx.x;
    if (idx >= 2 * 39 * 900) return;
    int u = idx % 900, dc = idx / 900;
    int c = dc % 39, d = dc / 39;
    int cs = c / 3, s = c - cs * 3;
    int p = u / 300, m = u - p * 300;
    const float* src = W + ((size_t)d * 900 + s * 300 + m) * 300 + p * 100;
    short8 sv;
#pragma unroll
    for (int i = 0; i < 8; ++i) {
        int cl = cs * 8 + i;
        sv[i] = (cl < 100) ? f2bf(src[cl]) : (short)0;
    }
    *(short8*)(dst + ((size_t)(d * 39 + c) * 912 + u) * 8) = sv;
}

// ---------------------------------------------------------------------------
// Pack attn Ur/Uw [6][300][300] -> [6][40][608][8sh]
// thread u=(p*300+m): p=0 cols [0,160), p=1 cols [160,300); rows Ur_m / Uw_m
// chunk c = cs*2+s (s=0:Ur, 1:Uw), cols 160p+8cs..+8 (0 beyond limit)
// ---------------------------------------------------------------------------
__global__ void k_pack_att(const float* __restrict__ Ur, const float* __restrict__ Uw,
                           short* __restrict__ dst)
{
    int idx = blockIdx.x * 256 + threadIdx.x;
    if (idx >= 6 * 40 * 600) return;
    int u = idx % 600, hc = idx / 600;
    int c = hc % 40, hd = hc / 40;
    int cs = c >> 1, s = c & 1;
    int p = u / 300, m = u - p * 300;
    int lim = p ? 140 : 160;
    const float* src = (s ? Uw : Ur) + ((size_t)hd * 300 + m) * 300 + 160 * p;
    short8 sv;
#pragma unroll
    for (int i = 0; i < 8; ++i) {
        int cl = cs * 8 + i;
        sv[i] = (cl < lim) ? f2bf(src[cl]) : (short)0;
    }
    *(short8*)(dst + ((size_t)(hd * 40 + c) * 608 + u) * 8) = sv;
}

// ---------------------------------------------------------------------------
// bf16 MFMA GEMM (B^T layout): C[r,c] = sum_k A[r,k]*B[c,k] + bias[c], f32 out
// ---------------------------------------------------------------------------
__global__ __launch_bounds__(256)
void k_mgemm(const short* __restrict__ A, const short* __restrict__ B,
             const float* __restrict__ bias, float* __restrict__ C,
             int R, int Cc)
{
    __shared__ short As[128 * 40];
    __shared__ short Bs[128 * 40];
    const int tid = threadIdx.x;
    const int r0 = blockIdx.y * 128, c0 = blockIdx.x * 128;
    const int w = tid >> 6, lane = tid & 63;
    const int m16 = lane & 15, quad = lane >> 4;
    const int wm = w & 1, wn = w >> 1;
    floatx4 acc[4][4];
#pragma unroll
    for (int i = 0; i < 4; ++i)
#pragma unroll
        for (int j = 0; j < 4; ++j) acc[i][j] = (floatx4){0.f, 0.f, 0.f, 0.f};

    const int ra0 = tid >> 2,         sa0 = tid & 3;
    const int ra1 = (tid + 256) >> 2, sa1 = tid & 3;

    for (int k0 = 0; k0 < KP; k0 += 32) {
        short8 za = {0,0,0,0,0,0,0,0};
        short8 a0 = za, a1 = za, b0 = za, b1 = za;
        if (r0 + ra0 < R) a0 = *(const short8*)(A + (size_t)(r0 + ra0) * KP + k0 + sa0 * 8);
        if (r0 + ra1 < R) a1 = *(const short8*)(A + (size_t)(r0 + ra1) * KP + k0 + sa1 * 8);
        if (c0 + ra0 < Cc) b0 = *(const short8*)(B + (size_t)(c0 + ra0) * KP + k0 + sa0 * 8);
        if (c0 + ra1 < Cc) b1 = *(const short8*)(B + (size_t)(c0 + ra1) * KP + k0 + sa1 * 8);
        *(short8*)(As + ra0 * 40 + sa0 * 8) = a0;
        *(short8*)(As + ra1 * 40 + sa1 * 8) = a1;
        *(short8*)(Bs + ra0 * 40 + sa0 * 8) = b0;
        *(short8*)(Bs + ra1 * 40 + sa1 * 8) = b1;
        __syncthreads();
        short8 af[4], bfr[4];
#pragma unroll
        for (int mt = 0; mt < 4; ++mt)
            af[mt] = *(const short8*)(As + (wm * 64 + mt * 16 + m16) * 40 + quad * 8);
#pragma unroll
        for (int nt = 0; nt < 4; ++nt)
            bfr[nt] = *(const short8*)(Bs + (wn * 64 + nt * 16 + m16) * 40 + quad * 8);
#pragma unroll
        for (int mt = 0; mt < 4; ++mt)
#pragma unroll
            for (int nt = 0; nt < 4; ++nt)
                acc[mt][nt] = __builtin_amdgcn_mfma_f32_16x16x32_bf16(
                    af[mt], bfr[nt], acc[mt][nt], 0, 0, 0);
        __syncthreads();
    }
#pragma unroll
    for (int mt = 0; mt < 4; ++mt) {
#pragma unroll
        for (int nt = 0; nt < 4; ++nt) {
            int col = c0 + wn * 64 + nt * 16 + m16;
            if (col >= Cc) continue;
            float bv = bias ? bias[col] : 0.f;
#pragma unroll
            for (int i = 0; i < 4; ++i) {
                int row = r0 + wm * 64 + mt * 16 + quad * 4 + i;
                if (row < R) C[(size_t)row * Cc + col] = acc[mt][nt][i] + bv;
            }
        }
    }
}

// ---------------------------------------------------------------------------
// f32 GEMM (small lin layer): C = act(A @ B^T + bias)
// ---------------------------------------------------------------------------
__global__ __launch_bounds__(256)
void k_gemm(const float* __restrict__ A, const float* __restrict__ B,
            const float* __restrict__ bias, float* __restrict__ C,
            int R, int Cc, int K, int actTanh)
{
    __shared__ __align__(16) float Asm[16][132];
    __shared__ __align__(16) float Bsm[16][132];
    const int tid = threadIdx.x;
    const int r0 = blockIdx.y * 128, c0 = blockIdx.x * 128;
    const int li = tid >> 1, lk = (tid & 1) * 8;
    const int tx = tid & 15, ty = tid >> 4;
    float acc[8][8];
#pragma unroll
    for (int i = 0; i < 8; ++i)
#pragma unroll
        for (int j = 0; j < 8; ++j) acc[i][j] = 0.f;
    const int nch = (K + 15) >> 4;
    for (int ch = 0; ch < nch; ++ch) {
        const int k0 = ch * 16;
        {
            float v[8];
            int gr = r0 + li, kb = k0 + lk;
            if (gr < R && kb + 8 <= K) {
                const float* p = A + (size_t)gr * K + kb;
                *(float4*)&v[0] = *(const float4*)p;
                *(float4*)&v[4] = *(const float4*)(p + 4);
            } else {
#pragma unroll
                for (int z = 0; z < 8; ++z) {
                    int k = kb + z;
                    v[z] = (gr < R && k < K) ? A[(size_t)gr * K + k] : 0.f;
                }
            }
#pragma unroll
            for (int z = 0; z < 8; ++z) Asm[lk + z][li] = v[z];
        }
        {
            float v[8];
            int gr = c0 + li, kb = k0 + lk;
            if (gr < Cc && kb + 8 <= K) {
                const float* p = B + (size_t)gr * K + kb;
                *(float4*)&v[0] = *(const float4*)p;
                *(float4*)&v[4] = *(const float4*)(p + 4);
            } else {
#pragma unroll
                for (int z = 0; z < 8; ++z) {
                    int k = kb + z;
                    v[z] = (gr < Cc && k < K) ? B[(size_t)gr * K + k] : 0.f;
                }
            }
#pragma unroll
            for (int z = 0; z < 8; ++z) Bsm[lk + z][li] = v[z];
        }
        __syncthreads();
#pragma unroll
        for (int kk = 0; kk < 16; ++kk) {
            float a[8], b[8];
            *(float4*)&a[0] = *(const float4*)&Asm[kk][ty * 8];
            *(float4*)&a[4] = *(const float4*)&Asm[kk][ty * 8 + 4];
            *(float4*)&b[0] = *(const float4*)&Bsm[kk][tx * 8];
            *(float4*)&b[4] = *(const float4*)&Bsm[kk][tx * 8 + 4];
#pragma unroll
            for (int i = 0; i < 8; ++i)
#pragma unroll
                for (int j = 0; j < 8; ++j) acc[i][j] = fmaf(a[i], b[j], acc[i][j]);
        }
        __syncthreads();
    }
#pragma unroll
    for (int i = 0; i < 8; ++i) {
        int r = r0 + ty * 8 + i;
        if (r >= R) continue;
#pragma unroll
        for (int j = 0; j < 8; ++j) {
            int c = c0 + tx * 8 + j;
            if (c >= Cc) continue;
            float v = acc[i][j];
            if (bias) v += bias[c];
            if (actTanh) v = tanhf(v);
            C[(size_t)r * Cc + c] = v;
        }
    }
}

// ---------------------------------------------------------------------------
// GRU scan core (utt & ctx): 960 threads, thread u=(p,m) owns 3 gate-rows over
// cols [100p,100p+100). Chunks 0..8 LDS-resident (loaded once), 9..38 streamed
// per step with a depth-6 ring. h broadcast from LDS. No VGPR-resident weights.
// ---------------------------------------------------------------------------
template<bool IS_UTT>
__device__ __forceinline__ void gru_scan_body(
    const short* __restrict__ Wp,   // [2][39][912][8sh]
    const float* __restrict__ bhh,
    const float* __restrict__ gi,   // [T*NB][1800]
    int d, int chain, int NB, int len,
    float* __restrict__ outp)       // maxpool row (utt) or hout base (ctx)
{
    extern __shared__ char smem[];
    short* wlds = (short*)smem;                               // [9][912][8]
    float* hs   = (float*)(smem + (size_t)GRU_RES * 912 * 16);// [304]
    float* pds  = hs + 304;                                   // [3][3][300]
    const int tid = threadIdx.x;
    const int p = tid / 300, m = tid - p * 300;  // valid for tid<900
    const uint4* wall = (const uint4*)(Wp + (size_t)d * 39 * 912 * 8);
    if (tid < 912) {
#pragma unroll
        for (int c = 0; c < GRU_RES; ++c)
            *(uint4*)(wlds + ((size_t)c * 912 + tid) * 8) = wall[(size_t)c * 912 + tid];
    }
    if (tid < 304) hs[tid] = 0.f;
    float br = 0.f, bz = 0.f, bn = 0.f;
    if (tid < 300) {
        br = bhh[d * 900 + tid];
        bz = bhh[d * 900 + 300 + tid];
        bn = bhh[d * 900 + 600 + tid];
    }
    float mx = -1e30f;
    __syncthreads();
    for (int t = 0; t < len; ++t) {
        int ts = d ? (len - 1 - t) : t;
        float g0 = 0.f, g1 = 0.f, g2 = 0.f;
        if (tid < 300) {   // prefetch gate inputs (used after the barrier)
            size_t row = ((size_t)(ts * NB + chain)) * 1800 + d * 900 + tid;
            g0 = gi[row]; g1 = gi[row + 300]; g2 = gi[row + 600];
        }
        if (tid < 900) {
            const int hb = 100 * p;
            float a0 = 0.f, a1 = 0.f, a2 = 0.f;
            uint4 ring[6];
#pragma unroll
            for (int i = 0; i < 6; ++i) ring[i] = wall[(size_t)(GRU_RES + i) * 912 + tid];
            // LDS-resident chunks 0..8 (cs 0..2, all s) — overlaps ring latency
#pragma unroll
            for (int c = 0; c < GRU_RES; ++c) {
                int cs = c / 3, s = c - 3 * cs;
                float4 h0 = *(const float4*)&hs[hb + 8 * cs];
                float4 h1 = *(const float4*)&hs[hb + 8 * cs + 4];
                uint4 wv = *(const uint4*)(wlds + ((size_t)c * 912 + tid) * 8);
                if (s == 0) dot8(wv, h0, h1, a0);
                else if (s == 1) dot8(wv, h0, h1, a1);
                else dot8(wv, h0, h1, a2);
            }
            // streamed chunks 9..38
#pragma unroll
            for (int i = 0; i < 39 - GRU_RES; ++i) {
                int c = GRU_RES + i, cs = c / 3, s = c - 3 * cs;
                uint4 wv = ring[i % 6];
                if (i + 6 < 39 - GRU_RES)
                    ring[i % 6] = wall[(size_t)(c + 6) * 912 + tid];
                float4 h0 = *(const float4*)&hs[hb + 8 * cs];
                float4 h1 = *(const float4*)&hs[hb + 8 * cs + 4];
                if (s == 0) dot8(wv, h0, h1, a0);
                else if (s == 1) dot8(wv, h0, h1, a1);
                else dot8(wv, h0, h1, a2);
            }
            pds[(0 * 3 + p) * 300 + m] = a0;
            pds[(1 * 3 + p) * 300 + m] = a1;
            pds[(2 * 3 + p) * 300 + m] = a2;
        }
        __syncthreads();
        if (tid < 300) {
            float dr = pds[tid] + pds[300 + tid] + pds[600 + tid] + br;
            float dz = pds[900 + tid] + pds[1200 + tid] + pds[1500 + tid] + bz;
            float dn = pds[1800 + tid] + pds[2100 + tid] + pds[2400 + tid] + bn;
            float r = sigm(g0 + dr);
            float z = sigm(g1 + dz);
            float nv = tanhf(g2 + r * dn);
            float hv = (1.f - z) * nv + z * hs[tid];
            hs[tid] = hv;
            if (IS_UTT) mx = fmaxf(mx, hv);
            else outp[(size_t)ts * 300 + tid] = hv;
        }
        __syncthreads();
    }
    if (IS_UTT && tid < 300) {
        if (len < LL) mx = fmaxf(mx, 0.f);   // padded steps contribute 0
        outp[tid] = mx;
    }
}

__global__ __launch_bounds__(960, 1)
void k_utt_scan(const short* __restrict__ Wp, const float* __restrict__ bhh,
                const float* __restrict__ gi, const int* __restrict__ lens,
                float* __restrict__ maxpool)
{
    const int d = blockIdx.y, n = blockIdx.x;
    gru_scan_body<true>(Wp, bhh, gi, d, n, NN, lens[n],
                        maxpool + (size_t)n * 600 + d * 300);
}

__global__ __launch_bounds__(960, 1)
void k_ctx_scan(const short* __restrict__ Wp, const float* __restrict__ bhh,
                const float* __restrict__ gi, float* __restrict__ hout)
{
    const int d = blockIdx.y, q = blockIdx.x;
    gru_scan_body<false>(Wp, bhh, gi, d, q, NQ, KEFF,
                         hout + (((size_t)d * NQ + q) * KEFF) * 300);
}

// ---------------------------------------------------------------------------
__global__ void k_init_query(const float* __restrict__ u, float* __restrict__ query)
{
    int q = blockIdx.x;
    for (int e = threadIdx.x; e < 300; e += blockDim.x)
        query[(size_t)q * 300 + e] = u[(size_t)(q + 1) * 300 + e];
}

// ctx rows -> bf16 [5080][320] padded
__global__ void k_build_ctxA(const float* __restrict__ u, short* __restrict__ Actx)
{
    int rkq = blockIdx.x;            // k*127 + q
    int k = rkq / NQ, q = rkq - k * NQ;
    int src = q + 1 - KWIN + k;
    int e = threadIdx.x;             // 320 threads
    float v = (e < 300 && src >= 0) ? u[(size_t)src * 300 + e] : 0.f;
    Actx[(size_t)rkq * KP + e] = f2bf(v);
}

// ---------------------------------------------------------------------------
__global__ void k_combine(const float* __restrict__ u, const float* __restrict__ hout,
                          float* __restrict__ mem_bank, short* __restrict__ mrkq)
{
    int rkq = blockIdx.x;            // k*127 + q
    int k = rkq / NQ, q = rkq - k * NQ;
    int src = q + 1 - KWIN + k;
    int e = threadIdx.x;             // 320 threads
    float v = 0.f;
    if (e < 300) {
        float c = (src >= 0) ? u[(size_t)src * 300 + e] : 0.f;
        v = c + hout[((size_t)q * KEFF + k) * 300 + e]
              + hout[(((size_t)NQ + q) * KEFF + k) * 300 + e];
        mem_bank[((size_t)q * KEFF + k) * 300 + e] = v;
    }
    mrkq[(size_t)rkq * KP + e] = f2bf(v);
}

// ---------------------------------------------------------------------------
// AttnGRU scan + fused score/softmax. 640 threads; thread (p,m) owns rows
// {Ur_m, Uw_m} over cols [160p, 160p+{160,140}). Chunks 0..11 LDS-resident,
// 12..39 streamed with a depth-6 ring.
// ---------------------------------------------------------------------------
__global__ __launch_bounds__(640, 1)
void k_att_scan(const short* __restrict__ Wp,     // [6][40][608][8sh]
                const float* __restrict__ burb,   // [6*300]
                const float* __restrict__ bub,    // [6*300]
                const float* __restrict__ xgr,    // [5080][1800] f32
                const float* __restrict__ xgw,
                const float* __restrict__ query,  // [127][300]
                const float* __restrict__ membank,// [127][40][300]
                float* __restrict__ hbuf,         // [2][127][300]
                int hop)
{
    extern __shared__ char smem[];
    short* wlds  = (short*)smem;                               // [12][608][8]
    float* hs    = (float*)(smem + (size_t)ATT_RES * 608 * 16);// [320]
    float* pds   = hs + 320;                                   // [2][2][304]
    float* qv    = pds + 1216;                                 // [304]
    float* gates = qv + 304;                                   // [40]
    float* scr   = gates + 40;                                 // [40]
    const int d = blockIdx.y, q = blockIdx.x, tid = threadIdx.x;
    const int hd = hop * 2 + d;
    const int p = tid / 300, m = tid - p * 300;   // valid tid<600
    const uint4* wall = (const uint4*)(Wp + (size_t)hd * 40 * 608 * 8);
    if (tid < 608) {
#pragma unroll
        for (int c = 0; c < ATT_RES; ++c)
            *(uint4*)(wlds + ((size_t)c * 608 + tid) * 8) = wall[(size_t)c * 608 + tid];
    }
    if (tid < 320) {
        hs[tid] = 0.f;
        qv[tid] = (tid < 300) ? query[(size_t)q * 300 + tid] : 0.f;
    }
    float bur = 0.f, bu = 0.f;
    if (tid < 300) { bur = burb[hd * 300 + tid]; bu = bub[hd * 300 + tid]; }
    __syncthreads();
    // ---- fused scores: dot + masked softmax ----
    if (tid < 320) {
        int k = tid >> 3, part = tid & 7;
        const float* mrow = membank + ((size_t)q * KEFF + k) * 300;
        int e0 = part * 38, e1 = e0 + 38 > 300 ? 300 : e0 + 38;
        float acc = 0.f;
        for (int e = e0; e < e1; ++e) acc = fmaf(qv[e], mrow[e], acc);
        acc += __shfl_xor(acc, 1);
        acc += __shfl_xor(acc, 2);
        acc += __shfl_xor(acc, 4);
        if (part == 0) scr[k] = acc;
    }
    __syncthreads();
    if (tid < 64) {
        float s = (tid < KEFF) ? scr[tid] : -1e30f;
        if (tid < KWIN - 1 - q) s = -1e10f;     // zero-padded slots masked
        float mxs = s;
        for (int o = 32; o > 0; o >>= 1) mxs = fmaxf(mxs, __shfl_xor(mxs, o));
        float e = (tid < KEFF) ? __expf(s - mxs) : 0.f;
        float sm = e;
        for (int o = 32; o > 0; o >>= 1) sm += __shfl_xor(sm, o);
        if (tid < KEFF) gates[tid] = e / sm;
    }
    __syncthreads();
    // ---- scan ----
    for (int t = 0; t < KEFF; ++t) {
        int kq = d ? (KEFF - 1 - t) : t;
        float xr = 0.f, xw = 0.f, gt = 0.f;
        if (tid < 300) {
            size_t xi = ((size_t)(kq * NQ + q)) * 1800 + (size_t)hd * 300 + tid;
            xr = xgr[xi]; xw = xgw[xi];
            gt = gates[kq];
        }
        if (tid < 600) {
            const int hb = 160 * p;
            float a0 = 0.f, a1 = 0.f;
            uint4 ring[6];
#pragma unroll
            for (int i = 0; i < 6; ++i) ring[i] = wall[(size_t)(ATT_RES + i) * 608 + tid];
            // LDS-resident chunks 0..11 (cs 0..5, both s)
#pragma unroll
            for (int c = 0; c < ATT_RES; ++c) {
                int cs = c >> 1, s = c & 1;
                float4 h0 = *(const float4*)&hs[hb + 8 * cs];
                float4 h1 = *(const float4*)&hs[hb + 8 * cs + 4];
                uint4 wv = *(const uint4*)(wlds + ((size_t)c * 608 + tid) * 8);
                if (s == 0) dot8(wv, h0, h1, a0);
                else dot8(wv, h0, h1, a1);
            }
            // streamed chunks 12..39
#pragma unroll
            for (int i = 0; i < 40 - ATT_RES; ++i) {
                int c = ATT_RES + i, cs = c >> 1, s = c & 1;
                uint4 wv = ring[i % 6];
                if (i + 6 < 40 - ATT_RES)
                    ring[i % 6] = wall[(size_t)(c + 6) * 608 + tid];
                float4 h0 = *(const float4*)&hs[hb + 8 * cs];
                float4 h1 = *(const float4*)&hs[hb + 8 * cs + 4];
                if (s == 0) dot8(wv, h0, h1, a0);
                else dot8(wv, h0, h1, a1);
            }
            pds[(0 * 2 + p) * 304 + m] = a0;
            pds[(1 * 2 + p) * 304 + m] = a1;
        }
        __syncthreads();
        if (tid < 300) {
            float dr = pds[tid] + pds[304 + tid] + bur;
            float dw = pds[608 + tid] + pds[912 + tid] + bu;
            float r = sigm(xr + dr);
            float ht = tanhf(xw + r * dw);
            hs[tid] = gt * ht + (1.f - gt) * hs[tid];
        }
        __syncthreads();
    }
    if (tid < 300)
        hbuf[((size_t)d * NQ + q) * 300 + tid] = hs[tid];
}

__global__ void k_qupd(float* __restrict__ query, const float* __restrict__ hbuf)
{
    int q = blockIdx.x;
    for (int e = threadIdx.x; e < 300; e += blockDim.x)
        query[(size_t)q * 300 + e] += hbuf[(size_t)q * 300 + e]
                                    + hbuf[(size_t)(NQ + q) * 300 + e];
}

// ---------------------------------------------------------------------------
__global__ __launch_bounds__(64)
void k_cls(const float* __restrict__ u, const float* __restrict__ query,
           const float* __restrict__ cw, const float* __restrict__ cb,
           float* __restrict__ out)
{
    int n = blockIdx.x;
    const float* srow = (n == 0) ? u : (query + (size_t)(n - 1) * 300);
    int c = threadIdx.x & 7;
    int part = threadIdx.x >> 3;
    float p = 0.f;
    if (c < NCLS) {
        for (int e = part; e < 300; e += 8) p = fmaf(srow[e], cw[c * 300 + e], p);
    }
    p += __shfl_xor(p, 8);
    p += __shfl_xor(p, 16);
    p += __shfl_xor(p, 32);
    if (part == 0 && c < NCLS) out[n * NCLS + c] = p + cb[c];
}

// ---------------------------------------------------------------------------
extern "C" void kernel_launch(void* const* d_in, const int* in_sizes, int n_in,
                              void* d_out, int out_size, void* d_ws, size_t ws_size,
                              hipStream_t stream)
{
    const int* ids  = (const int*)d_in[0];
    const int* lens = (const int*)d_in[1];
    const float* emb   = (const float*)d_in[2];
    const float* uWih  = (const float*)d_in[3];
    const float* uWhh  = (const float*)d_in[4];
    const float* ubih  = (const float*)d_in[5];
    const float* ubhh  = (const float*)d_in[6];
    const float* linw  = (const float*)d_in[7];
    const float* linb  = (const float*)d_in[8];
    const float* cWih  = (const float*)d_in[9];
    const float* cWhh  = (const float*)d_in[10];
    const float* cbih  = (const float*)d_in[11];
    const float* cbhh  = (const float*)d_in[12];
    const float* aWr_w = (const float*)d_in[13];
    const float* aWr_b = (const float*)d_in[14];
    const float* aUr_w = (const float*)d_in[15];
    const float* aUr_b = (const float*)d_in[16];
    const float* aW_w  = (const float*)d_in[17];
    const float* aW_b  = (const float*)d_in[18];
    const float* aU_w  = (const float*)d_in[19];
    const float* aU_b  = (const float*)d_in[20];
    const float* clsw  = (const float*)d_in[21];
    const float* clsb  = (const float*)d_in[22];
    float* out = (float*)d_out;
    (void)in_sizes; (void)n_in; (void)out_size; (void)ws_size;

    // opt-in to >64KB dynamic LDS (validated working in R6)
    (void)hipFuncSetAttribute((const void*)k_utt_scan,
            hipFuncAttributeMaxDynamicSharedMemorySize, (int)GRU_LDS);
    (void)hipFuncSetAttribute((const void*)k_ctx_scan,
            hipFuncAttributeMaxDynamicSharedMemorySize, (int)GRU_LDS);
    (void)hipFuncSetAttribute((const void*)k_att_scan,
            hipFuncAttributeMaxDynamicSharedMemorySize, (int)ATT_LDS);

    char* base = (char*)d_ws;
    size_t off = 0;
    auto alloc = [&](size_t b) -> void* {
        void* r = (void*)(base + off);
        off += (b + 255) & ~(size_t)255;
        return r;
    };
    short* A_utt  = (short*)alloc((size_t)8192 * KP * 2);          //  5.2 MB
    float* giU    = (float*)alloc((size_t)8192 * 1800 * 4);        // 59.0 MB (reused: xgr)
    float* giC    = (float*)alloc((size_t)5080 * 1800 * 4);        // 36.6 MB (reused: xgw)
    short* wUihB  = (short*)alloc((size_t)1800 * KP * 2);
    short* wCihB  = (short*)alloc((size_t)1800 * KP * 2);
    short* wArB   = (short*)alloc((size_t)1800 * KP * 2);
    short* wAwB   = (short*)alloc((size_t)1800 * KP * 2);
    short* wPackU = (short*)alloc((size_t)2 * 39 * 912 * 8 * 2);   // 1.14 MB
    short* wPackC = (short*)alloc((size_t)2 * 39 * 912 * 8 * 2);
    short* wPackA = (short*)alloc((size_t)6 * 40 * 608 * 8 * 2);   // 2.33 MB
    short* Actx   = (short*)alloc((size_t)5080 * KP * 2);
    float* hout   = (float*)alloc((size_t)2 * NQ * KEFF * 300 * 4);
    float* membank= (float*)alloc((size_t)NQ * KEFF * 300 * 4);
    short* mrkq   = (short*)alloc((size_t)5080 * KP * 2);
    float* mpool  = (float*)alloc((size_t)NN * 600 * 4);
    float* uu     = (float*)alloc((size_t)NN * 300 * 4);
    float* query  = (float*)alloc((size_t)NQ * 300 * 4);
    float* hbuf   = (float*)alloc((size_t)2 * NQ * 300 * 4);
    float* xgr = giU;   // giU dead after k_utt_scan
    float* xgw = giC;   // giC dead after k_ctx_scan

    const int RKQ = NQ * KEFF;  // 5080

    // 0) weight conversions / packing
    k_conv320<<<dim3(1800), dim3(320), 0, stream>>>(uWih, wUihB);
    k_conv320<<<dim3(1800), dim3(320), 0, stream>>>(cWih, wCihB);
    k_conv320<<<dim3(1800), dim3(320), 0, stream>>>(aWr_w, wArB);
    k_conv320<<<dim3(1800), dim3(320), 0, stream>>>(aW_w, wAwB);
    k_pack_gru<<<dim3((2 * 39 * 900 + 255) / 256), dim3(256), 0, stream>>>(uWhh, wPackU);
    k_pack_gru<<<dim3((2 * 39 * 900 + 255) / 256), dim3(256), 0, stream>>>(cWhh, wPackC);
    k_pack_att<<<dim3((6 * 40 * 600 + 255) / 256), dim3(256), 0, stream>>>(aUr_w, aU_w, wPackA);

    // 1) gather, 2) utt input-gate GEMM (MFMA), 3) utt scan + maxpool
    k_gather_bf16<<<dim3(LL * NN), dim3(320), 0, stream>>>(emb, ids, A_utt);
    k_mgemm<<<dim3(15, 64), dim3(256), 0, stream>>>(A_utt, wUihB, ubih, giU, 8192, 1800);
    k_utt_scan<<<dim3(NN, 2), dim3(960), GRU_LDS, stream>>>(wPackU, ubhh, giU, lens, mpool);
    // 4) u = tanh(maxpool @ lin_w.T + lin_b)
    k_gemm<<<dim3(3, 1), dim3(256), 0, stream>>>(mpool, linw, linb, uu, NN, 300, 600, 1);
    // 5) query init + ctx rows
    k_init_query<<<dim3(NQ), dim3(128), 0, stream>>>(uu, query);
    k_build_ctxA<<<dim3(RKQ), dim3(320), 0, stream>>>(uu, Actx);
    // 6) ctx input-gate GEMM + ctx scan + combine
    k_mgemm<<<dim3(15, 40), dim3(256), 0, stream>>>(Actx, wCihB, cbih, giC, RKQ, 1800);
    k_ctx_scan<<<dim3(NQ, 2), dim3(960), GRU_LDS, stream>>>(wPackC, cbhh, giC, hout);
    k_combine<<<dim3(RKQ), dim3(320), 0, stream>>>(uu, hout, membank, mrkq);
    // 7) attention x-projections (all hops/dirs)
    k_mgemm<<<dim3(15, 40), dim3(256), 0, stream>>>(mrkq, wArB, aWr_b, xgr, RKQ, 1800);
    k_mgemm<<<dim3(15, 40), dim3(256), 0, stream>>>(mrkq, wAwB, aW_b, xgw, RKQ, 1800);
    // 8) hops (scores fused into att_scan)
    for (int hop = 0; hop < 3; ++hop) {
        k_att_scan<<<dim3(NQ, 2), dim3(640), ATT_LDS, stream>>>(
            wPackA, aUr_b, aU_b, xgr, xgw, query, membank, hbuf, hop);
        k_qupd<<<dim3(NQ), dim3(128), 0, stream>>>(query, hbuf);
    }
    // 9) classifier
    k_cls<<<dim3(NN), dim3(64), 0, stream>>>(uu, query, clsw, clsb, out);
}

// Round 8
// 1296.686 us; speedup vs baseline: 6.2644x; 1.0285x over previous
//
#include <hip/hip_runtime.h>

// ---- static config ----
static constexpr int NN   = 128;   // dialogues
static constexpr int LL   = 64;    // utterance length
static constexpr int KWIN = 40;
static constexpr int KEFF = 40;
static constexpr int NQ   = 127;   // N-1
static constexpr int NCLS = 6;
static constexpr int KP   = 320;   // padded K for MFMA GEMMs (300 -> 320)

// GRU scans: 39 chunks = 10 LDS-resident + 29 streamed (ring depth 6)
// att scans: 40 chunks = 15 LDS-resident + 25 streamed
static constexpr int GRU_RES = 10;
static constexpr int ATT_RES = 15;
static constexpr size_t GRU_LDS = (size_t)GRU_RES * 912 * 16 + (304 + 2700) * 4;               // 157,936
static constexpr size_t ATT_LDS = (size_t)ATT_RES * 608 * 16 + (320 + 1216 + 304 + 40 + 40) * 4; // 153,600

typedef __attribute__((ext_vector_type(8))) short short8;
typedef __attribute__((ext_vector_type(4))) float floatx4;

__device__ __forceinline__ float sigm(float x) { return 1.f / (1.f + __expf(-x)); }
__device__ __forceinline__ short f2bf(float f) {
    unsigned x = __float_as_uint(f);
    unsigned r = (x + 0x7fffu + ((x >> 16) & 1u)) >> 16;
    return (short)r;
}
__device__ __forceinline__ void bfp(unsigned v, float& lo, float& hi) {
    lo = __uint_as_float(v << 16);
    hi = __uint_as_float(v & 0xffff0000u);
}
__device__ __forceinline__ void dot8(uint4 wv, float4 h0, float4 h1, float& acc) {
    float l0, u0, l1, u1, l2, u2, l3, u3;
    bfp(wv.x, l0, u0); bfp(wv.y, l1, u1);
    bfp(wv.z, l2, u2); bfp(wv.w, l3, u3);
    acc = fmaf(l0, h0.x, acc); acc = fmaf(u0, h0.y, acc);
    acc = fmaf(l1, h0.z, acc); acc = fmaf(u1, h0.w, acc);
    acc = fmaf(l2, h1.x, acc); acc = fmaf(u2, h1.y, acc);
    acc = fmaf(l3, h1.z, acc); acc = fmaf(u3, h1.w, acc);
}

// ---------------------------------------------------------------------------
// Gather + convert: A[r=t*128+n][0..319] = bf16(emb[ids[n*64+t]]), zero-pad
// ---------------------------------------------------------------------------
__global__ void k_gather_bf16(const float* __restrict__ emb,
                              const int* __restrict__ ids,
                              short* __restrict__ A)
{
    int r = blockIdx.x;            // t*128 + n
    int n = r & (NN - 1);
    int t = r >> 7;
    int id = ids[n * LL + t];
    int e = threadIdx.x;           // 320 threads
    float v = (e < 300) ? emb[(size_t)id * 300 + e] : 0.f;
    A[(size_t)r * KP + e] = f2bf(v);
}

// 4 fused f32 [1800][300] -> bf16 [1800][320] conversions (blockIdx.y selects)
__global__ void k_conv4(const float* __restrict__ s0, const float* __restrict__ s1,
                        const float* __restrict__ s2, const float* __restrict__ s3,
                        short* __restrict__ d0, short* __restrict__ d1,
                        short* __restrict__ d2, short* __restrict__ d3)
{
    int which = blockIdx.y;
    const float* s = (which == 0) ? s0 : (which == 1) ? s1 : (which == 2) ? s2 : s3;
    short* d = (which == 0) ? d0 : (which == 1) ? d1 : (which == 2) ? d2 : d3;
    int r = blockIdx.x, e = threadIdx.x;   // 320 threads
    float v = (e < 300) ? s[(size_t)r * 300 + e] : 0.f;
    d[(size_t)r * KP + e] = f2bf(v);
}

// ---------------------------------------------------------------------------
// Pack GRU Whh [2][900][300] f32 -> chunk-interleaved bf16 [2][39][912][8sh]
// Fused for both GRUs (blockIdx.y: 0=utt, 1=ctx).
// thread u=(p*300+m) owns rows {m, m+300, m+600} cols [100p,100p+100)
// chunk c = cs*3+s : 8 bf16 of row (s*300+m), cols 100p+8cs..+8 (0 if >=100)
// ---------------------------------------------------------------------------
__global__ void k_pack_gru2(const float* __restrict__ W0, const float* __restrict__ W1,
                            short* __restrict__ d0, short* __restrict__ d1)
{
    const float* W = blockIdx.y ? W1 : W0;
    short* dst = blockIdx.y ? d1 : d0;
    int idx = blockIdx.x * 256 + threadIdx.x;
    if (idx >= 2 * 39 * 900) return;
    int u = idx % 900, dc = idx / 900;
    int c = dc % 39, d = dc / 39;
    int cs = c / 3, s = c - cs * 3;
    int p = u / 300, m = u - p * 300;
    const float* src = W + ((size_t)d * 900 + s * 300 + m) * 300 + p * 100;
    short8 sv;
#pragma unroll
    for (int i = 0; i < 8; ++i) {
        int cl = cs * 8 + i;
        sv[i] = (cl < 100) ? f2bf(src[cl]) : (short)0;
    }
    *(short8*)(dst + ((size_t)(d * 39 + c) * 912 + u) * 8) = sv;
}

// ---------------------------------------------------------------------------
// Pack attn Ur/Uw [6][300][300] -> [6][40][608][8sh]
// thread u=(p*300+m): p=0 cols [0,160), p=1 cols [160,300); rows Ur_m / Uw_m
// ---------------------------------------------------------------------------
__global__ void k_pack_att(const float* __restrict__ Ur, const float* __restrict__ Uw,
                           short* __restrict__ dst)
{
    int idx = blockIdx.x * 256 + threadIdx.x;
    if (idx >= 6 * 40 * 600) return;
    int u = idx % 600, hc = idx / 600;
    int c = hc % 40, hd = hc / 40;
    int cs = c >> 1, s = c & 1;
    int p = u / 300, m = u - p * 300;
    int lim = p ? 140 : 160;
    const float* src = (s ? Uw : Ur) + ((size_t)hd * 300 + m) * 300 + 160 * p;
    short8 sv;
#pragma unroll
    for (int i = 0; i < 8; ++i) {
        int cl = cs * 8 + i;
        sv[i] = (cl < lim) ? f2bf(src[cl]) : (short)0;
    }
    *(short8*)(dst + ((size_t)(hd * 40 + c) * 608 + u) * 8) = sv;
}

// ---------------------------------------------------------------------------
// bf16 MFMA GEMM (B^T layout), software-pipelined staging:
// register-prefetch tile k+1 before the MFMA block so the global latency
// hides under MFMA + frag reads instead of serializing at the barrier.
// ---------------------------------------------------------------------------
__global__ __launch_bounds__(256)
void k_mgemm(const short* __restrict__ A, const short* __restrict__ B,
             const float* __restrict__ bias, float* __restrict__ C,
             int R, int Cc)
{
    __shared__ short As[128 * 40];
    __shared__ short Bs[128 * 40];
    const int tid = threadIdx.x;
    const int r0 = blockIdx.y * 128, c0 = blockIdx.x * 128;
    const int w = tid >> 6, lane = tid & 63;
    const int m16 = lane & 15, quad = lane >> 4;
    const int wm = w & 1, wn = w >> 1;
    floatx4 acc[4][4];
#pragma unroll
    for (int i = 0; i < 4; ++i)
#pragma unroll
        for (int j = 0; j < 4; ++j) acc[i][j] = (floatx4){0.f, 0.f, 0.f, 0.f};

    const int ra0 = tid >> 2,         sa0 = tid & 3;
    const int ra1 = (tid + 256) >> 2, sa1 = tid & 3;
    const short8 za = {0,0,0,0,0,0,0,0};
    short8 na0 = za, na1 = za, nb0 = za, nb1 = za;
    if (r0 + ra0 < R)  na0 = *(const short8*)(A + (size_t)(r0 + ra0) * KP + sa0 * 8);
    if (r0 + ra1 < R)  na1 = *(const short8*)(A + (size_t)(r0 + ra1) * KP + sa1 * 8);
    if (c0 + ra0 < Cc) nb0 = *(const short8*)(B + (size_t)(c0 + ra0) * KP + sa0 * 8);
    if (c0 + ra1 < Cc) nb1 = *(const short8*)(B + (size_t)(c0 + ra1) * KP + sa1 * 8);

#pragma unroll
    for (int it = 0; it < KP / 32; ++it) {
        *(short8*)(As + ra0 * 40 + sa0 * 8) = na0;
        *(short8*)(As + ra1 * 40 + sa1 * 8) = na1;
        *(short8*)(Bs + ra0 * 40 + sa0 * 8) = nb0;
        *(short8*)(Bs + ra1 * 40 + sa1 * 8) = nb1;
        __syncthreads();
        if (it + 1 < KP / 32) {
            const int k0 = (it + 1) * 32;
            na0 = za; na1 = za; nb0 = za; nb1 = za;
            if (r0 + ra0 < R)  na0 = *(const short8*)(A + (size_t)(r0 + ra0) * KP + k0 + sa0 * 8);
            if (r0 + ra1 < R)  na1 = *(const short8*)(A + (size_t)(r0 + ra1) * KP + k0 + sa1 * 8);
            if (c0 + ra0 < Cc) nb0 = *(const short8*)(B + (size_t)(c0 + ra0) * KP + k0 + sa0 * 8);
            if (c0 + ra1 < Cc) nb1 = *(const short8*)(B + (size_t)(c0 + ra1) * KP + k0 + sa1 * 8);
        }
        short8 af[4], bfr[4];
#pragma unroll
        for (int mt = 0; mt < 4; ++mt)
            af[mt] = *(const short8*)(As + (wm * 64 + mt * 16 + m16) * 40 + quad * 8);
#pragma unroll
        for (int nt = 0; nt < 4; ++nt)
            bfr[nt] = *(const short8*)(Bs + (wn * 64 + nt * 16 + m16) * 40 + quad * 8);
#pragma unroll
        for (int mt = 0; mt < 4; ++mt)
#pragma unroll
            for (int nt = 0; nt < 4; ++nt)
                acc[mt][nt] = __builtin_amdgcn_mfma_f32_16x16x32_bf16(
                    af[mt], bfr[nt], acc[mt][nt], 0, 0, 0);
        __syncthreads();
    }
#pragma unroll
    for (int mt = 0; mt < 4; ++mt) {
#pragma unroll
        for (int nt = 0; nt < 4; ++nt) {
            int col = c0 + wn * 64 + nt * 16 + m16;
            if (col >= Cc) continue;
            float bv = bias ? bias[col] : 0.f;
#pragma unroll
            for (int i = 0; i < 4; ++i) {
                int row = r0 + wm * 64 + mt * 16 + quad * 4 + i;
                if (row < R) C[(size_t)row * Cc + col] = acc[mt][nt][i] + bv;
            }
        }
    }
}

// ---------------------------------------------------------------------------
// f32 GEMM (small lin layer): C = act(A @ B^T + bias)
// ---------------------------------------------------------------------------
__global__ __launch_bounds__(256)
void k_gemm(const float* __restrict__ A, const float* __restrict__ B,
            const float* __restrict__ bias, float* __restrict__ C,
            int R, int Cc, int K, int actTanh)
{
    __shared__ __align__(16) float Asm[16][132];
    __shared__ __align__(16) float Bsm[16][132];
    const int tid = threadIdx.x;
    const int r0 = blockIdx.y * 128, c0 = blockIdx.x * 128;
    const int li = tid >> 1, lk = (tid & 1) * 8;
    const int tx = tid & 15, ty = tid >> 4;
    float acc[8][8];
#pragma unroll
    for (int i = 0; i < 8; ++i)
#pragma unroll
        for (int j = 0; j < 8; ++j) acc[i][j] = 0.f;
    const int nch = (K + 15) >> 4;
    for (int ch = 0; ch < nch; ++ch) {
        const int k0 = ch * 16;
        {
            float v[8];
            int gr = r0 + li, kb = k0 + lk;
            if (gr < R && kb + 8 <= K) {
                const float* p = A + (size_t)gr * K + kb;
                *(float4*)&v[0] = *(const float4*)p;
                *(float4*)&v[4] = *(const float4*)(p + 4);
            } else {
#pragma unroll
                for (int z = 0; z < 8; ++z) {
                    int k = kb + z;
                    v[z] = (gr < R && k < K) ? A[(size_t)gr * K + k] : 0.f;
                }
            }
#pragma unroll
            for (int z = 0; z < 8; ++z) Asm[lk + z][li] = v[z];
        }
        {
            float v[8];
            int gr = c0 + li, kb = k0 + lk;
            if (gr < Cc && kb + 8 <= K) {
                const float* p = B + (size_t)gr * K + kb;
                *(float4*)&v[0] = *(const float4*)p;
                *(float4*)&v[4] = *(const float4*)(p + 4);
            } else {
#pragma unroll
                for (int z = 0; z < 8; ++z) {
                    int k = kb + z;
                    v[z] = (gr < Cc && k < K) ? B[(size_t)gr * K + k] : 0.f;
                }
            }
#pragma unroll
            for (int z = 0; z < 8; ++z) Bsm[lk + z][li] = v[z];
        }
        __syncthreads();
#pragma unroll
        for (int kk = 0; kk < 16; ++kk) {
            float a[8], b[8];
            *(float4*)&a[0] = *(const float4*)&Asm[kk][ty * 8];
            *(float4*)&a[4] = *(const float4*)&Asm[kk][ty * 8 + 4];
            *(float4*)&b[0] = *(const float4*)&Bsm[kk][tx * 8];
            *(float4*)&b[4] = *(const float4*)&Bsm[kk][tx * 8 + 4];
#pragma unroll
            for (int i = 0; i < 8; ++i)
#pragma unroll
                for (int j = 0; j < 8; ++j) acc[i][j] = fmaf(a[i], b[j], acc[i][j]);
        }
        __syncthreads();
    }
#pragma unroll
    for (int i = 0; i < 8; ++i) {
        int r = r0 + ty * 8 + i;
        if (r >= R) continue;
#pragma unroll
        for (int j = 0; j < 8; ++j) {
            int c = c0 + tx * 8 + j;
            if (c >= Cc) continue;
            float v = acc[i][j];
            if (bias) v += bias[c];
            if (actTanh) v = tanhf(v);
            C[(size_t)r * Cc + c] = v;
        }
    }
}

// ---------------------------------------------------------------------------
// GRU scan core (utt & ctx): 960 threads, thread u=(p,m) owns 3 gate-rows over
// cols [100p,100p+100). Chunks 0..9 LDS-resident (loaded once), 10..38 streamed
// per step with a depth-6 ring. h broadcast from LDS. No VGPR-resident weights.
// ---------------------------------------------------------------------------
template<bool IS_UTT>
__device__ __forceinline__ void gru_scan_body(
    const short* __restrict__ Wp,   // [2][39][912][8sh]
    const float* __restrict__ bhh,
    const float* __restrict__ gi,   // [T*NB][1800]
    int d, int chain, int NB, int len,
    float* __restrict__ outp)       // maxpool row (utt) or hout base (ctx)
{
    extern __shared__ char smem[];
    short* wlds = (short*)smem;                               // [10][912][8]
    float* hs   = (float*)(smem + (size_t)GRU_RES * 912 * 16);// [304]
    float* pds  = hs + 304;                                   // [3][3][300]
    const int tid = threadIdx.x;
    const int p = tid / 300, m = tid - p * 300;  // valid for tid<900
    const uint4* wall = (const uint4*)(Wp + (size_t)d * 39 * 912 * 8);
    if (tid < 912) {
#pragma unroll
        for (int c = 0; c < GRU_RES; ++c)
            *(uint4*)(wlds + ((size_t)c * 912 + tid) * 8) = wall[(size_t)c * 912 + tid];
    }
    if (tid < 304) hs[tid] = 0.f;
    float br = 0.f, bz = 0.f, bn = 0.f;
    if (tid < 300) {
        br = bhh[d * 900 + tid];
        bz = bhh[d * 900 + 300 + tid];
        bn = bhh[d * 900 + 600 + tid];
    }
    float mx = -1e30f;
    __syncthreads();
    for (int t = 0; t < len; ++t) {
        int ts = d ? (len - 1 - t) : t;
        float g0 = 0.f, g1 = 0.f, g2 = 0.f;
        if (tid < 300) {   // prefetch gate inputs (used after the barrier)
            size_t row = ((size_t)(ts * NB + chain)) * 1800 + d * 900 + tid;
            g0 = gi[row]; g1 = gi[row + 300]; g2 = gi[row + 600];
        }
        if (tid < 900) {
            const int hb = 100 * p;
            float a0 = 0.f, a1 = 0.f, a2 = 0.f;
            uint4 ring[6];
#pragma unroll
            for (int i = 0; i < 6; ++i) ring[i] = wall[(size_t)(GRU_RES + i) * 912 + tid];
            // LDS-resident chunks — overlap ring latency
#pragma unroll
            for (int c = 0; c < GRU_RES; ++c) {
                int cs = c / 3, s = c - 3 * cs;
                float4 h0 = *(const float4*)&hs[hb + 8 * cs];
                float4 h1 = *(const float4*)&hs[hb + 8 * cs + 4];
                uint4 wv = *(const uint4*)(wlds + ((size_t)c * 912 + tid) * 8);
                if (s == 0) dot8(wv, h0, h1, a0);
                else if (s == 1) dot8(wv, h0, h1, a1);
                else dot8(wv, h0, h1, a2);
            }
            // streamed chunks
#pragma unroll
            for (int i = 0; i < 39 - GRU_RES; ++i) {
                int c = GRU_RES + i, cs = c / 3, s = c - 3 * cs;
                uint4 wv = ring[i % 6];
                if (i + 6 < 39 - GRU_RES)
                    ring[i % 6] = wall[(size_t)(c + 6) * 912 + tid];
                float4 h0 = *(const float4*)&hs[hb + 8 * cs];
                float4 h1 = *(const float4*)&hs[hb + 8 * cs + 4];
                if (s == 0) dot8(wv, h0, h1, a0);
                else if (s == 1) dot8(wv, h0, h1, a1);
                else dot8(wv, h0, h1, a2);
            }
            pds[(0 * 3 + p) * 300 + m] = a0;
            pds[(1 * 3 + p) * 300 + m] = a1;
            pds[(2 * 3 + p) * 300 + m] = a2;
        }
        __syncthreads();
        if (tid < 300) {
            float dr = pds[tid] + pds[300 + tid] + pds[600 + tid] + br;
            float dz = pds[900 + tid] + pds[1200 + tid] + pds[1500 + tid] + bz;
            float dn = pds[1800 + tid] + pds[2100 + tid] + pds[2400 + tid] + bn;
            float r = sigm(g0 + dr);
            float z = sigm(g1 + dz);
            float nv = tanhf(g2 + r * dn);
            float hv = (1.f - z) * nv + z * hs[tid];
            hs[tid] = hv;
            if (IS_UTT) mx = fmaxf(mx, hv);
            else outp[(size_t)ts * 300 + tid] = hv;
        }
        __syncthreads();
    }
    if (IS_UTT && tid < 300) {
        if (len < LL) mx = fmaxf(mx, 0.f);   // padded steps contribute 0
        outp[tid] = mx;
    }
}

__global__ __launch_bounds__(960, 1)
void k_utt_scan(const short* __restrict__ Wp, const float* __restrict__ bhh,
                const float* __restrict__ gi, const int* __restrict__ lens,
                float* __restrict__ maxpool)
{
    const int d = blockIdx.y, n = blockIdx.x;
    gru_scan_body<true>(Wp, bhh, gi, d, n, NN, lens[n],
                        maxpool + (size_t)n * 600 + d * 300);
}

__global__ __launch_bounds__(960, 1)
void k_ctx_scan(const short* __restrict__ Wp, const float* __restrict__ bhh,
                const float* __restrict__ gi, float* __restrict__ hout)
{
    const int d = blockIdx.y, q = blockIdx.x;
    gru_scan_body<false>(Wp, bhh, gi, d, q, NQ, KEFF,
                         hout + (((size_t)d * NQ + q) * KEFF) * 300);
}

// ---------------------------------------------------------------------------
// ctx rows -> bf16 [5080][320] padded; also initializes query (k==0 blocks)
// ---------------------------------------------------------------------------
__global__ void k_build_ctxA(const float* __restrict__ u, short* __restrict__ Actx,
                             float* __restrict__ query)
{
    int rkq = blockIdx.x;            // k*127 + q
    int k = rkq / NQ, q = rkq - k * NQ;
    int src = q + 1 - KWIN + k;
    int e = threadIdx.x;             // 320 threads
    float v = (e < 300 && src >= 0) ? u[(size_t)src * 300 + e] : 0.f;
    Actx[(size_t)rkq * KP + e] = f2bf(v);
    if (k == 0 && e < 300)
        query[(size_t)q * 300 + e] = u[(size_t)(q + 1) * 300 + e];
}

// ---------------------------------------------------------------------------
__global__ void k_combine(const float* __restrict__ u, const float* __restrict__ hout,
                          float* __restrict__ mem_bank, short* __restrict__ mrkq)
{
    int rkq = blockIdx.x;            // k*127 + q
    int k = rkq / NQ, q = rkq - k * NQ;
    int src = q + 1 - KWIN + k;
    int e = threadIdx.x;             // 320 threads
    float v = 0.f;
    if (e < 300) {
        float c = (src >= 0) ? u[(size_t)src * 300 + e] : 0.f;
        v = c + hout[((size_t)q * KEFF + k) * 300 + e]
              + hout[(((size_t)NQ + q) * KEFF + k) * 300 + e];
        mem_bank[((size_t)q * KEFF + k) * 300 + e] = v;
    }
    mrkq[(size_t)rkq * KP + e] = f2bf(v);
}

// ---------------------------------------------------------------------------
// AttnGRU scan + fused score/softmax. 640 threads; thread (p,m) owns rows
// {Ur_m, Uw_m} over cols [160p, 160p+{160,140}). Chunks 0..14 LDS-resident,
// 15..39 streamed with a depth-6 ring.
// ---------------------------------------------------------------------------
__global__ __launch_bounds__(640, 1)
void k_att_scan(const short* __restrict__ Wp,     // [6][40][608][8sh]
                const float* __restrict__ burb,   // [6*300]
                const float* __restrict__ bub,    // [6*300]
                const float* __restrict__ xgr,    // [5080][1800] f32
                const float* __restrict__ xgw,
                const float* __restrict__ query,  // [127][300]
                const float* __restrict__ membank,// [127][40][300]
                float* __restrict__ hbuf,         // [2][127][300]
                int hop)
{
    extern __shared__ char smem[];
    short* wlds  = (short*)smem;                               // [15][608][8]
    float* hs    = (float*)(smem + (size_t)ATT_RES * 608 * 16);// [320]
    float* pds   = hs + 320;                                   // [2][2][304]
    float* qv    = pds + 1216;                                 // [304]
    float* gates = qv + 304;                                   // [40]
    float* scr   = gates + 40;                                 // [40]
    const int d = blockIdx.y, q = blockIdx.x, tid = threadIdx.x;
    const int hd = hop * 2 + d;
    const int p = tid / 300, m = tid - p * 300;   // valid tid<600
    const uint4* wall = (const uint4*)(Wp + (size_t)hd * 40 * 608 * 8);
    if (tid < 608) {
#pragma unroll
        for (int c = 0; c < ATT_RES; ++c)
            *(uint4*)(wlds + ((size_t)c * 608 + tid) * 8) = wall[(size_t)c * 608 + tid];
    }
    if (tid < 320) {
        hs[tid] = 0.f;
        qv[tid] = (tid < 300) ? query[(size_t)q * 300 + tid] : 0.f;
    }
    float bur = 0.f, bu = 0.f;
    if (tid < 300) { bur = burb[hd * 300 + tid]; bu = bub[hd * 300 + tid]; }
    __syncthreads();
    // ---- fused scores: dot + masked softmax ----
    if (tid < 320) {
        int k = tid >> 3, part = tid & 7;
        const float* mrow = membank + ((size_t)q * KEFF + k) * 300;
        int e0 = part * 38, e1 = e0 + 38 > 300 ? 300 : e0 + 38;
        float acc = 0.f;
        for (int e = e0; e < e1; ++e) acc = fmaf(qv[e], mrow[e], acc);
        acc += __shfl_xor(acc, 1);
        acc += __shfl_xor(acc, 2);
        acc += __shfl_xor(acc, 4);
        if (part == 0) scr[k] = acc;
    }
    __syncthreads();
    if (tid < 64) {
        float s = (tid < KEFF) ? scr[tid] : -1e30f;
        if (tid < KWIN - 1 - q) s = -1e10f;     // zero-padded slots masked
        float mxs = s;
        for (int o = 32; o > 0; o >>= 1) mxs = fmaxf(mxs, __shfl_xor(mxs, o));
        float e = (tid < KEFF) ? __expf(s - mxs) : 0.f;
        float sm = e;
        for (int o = 32; o > 0; o >>= 1) sm += __shfl_xor(sm, o);
        if (tid < KEFF) gates[tid] = e / sm;
    }
    __syncthreads();
    // ---- scan ----
    for (int t = 0; t < KEFF; ++t) {
        int kq = d ? (KEFF - 1 - t) : t;
        float xr = 0.f, xw = 0.f, gt = 0.f;
        if (tid < 300) {
            size_t xi = ((size_t)(kq * NQ + q)) * 1800 + (size_t)hd * 300 + tid;
            xr = xgr[xi]; xw = xgw[xi];
            gt = gates[kq];
        }
        if (tid < 600) {
            const int hb = 160 * p;
            float a0 = 0.f, a1 = 0.f;
            uint4 ring[6];
#pragma unroll
            for (int i = 0; i < 6; ++i) ring[i] = wall[(size_t)(ATT_RES + i) * 608 + tid];
            // LDS-resident chunks
#pragma unroll
            for (int c = 0; c < ATT_RES; ++c) {
                int cs = c >> 1, s = c & 1;
                float4 h0 = *(const float4*)&hs[hb + 8 * cs];
                float4 h1 = *(const float4*)&hs[hb + 8 * cs + 4];
                uint4 wv = *(const uint4*)(wlds + ((size_t)c * 608 + tid) * 8);
                if (s == 0) dot8(wv, h0, h1, a0);
                else dot8(wv, h0, h1, a1);
            }
            // streamed chunks
#pragma unroll
            for (int i = 0; i < 40 - ATT_RES; ++i) {
                int c = ATT_RES + i, cs = c >> 1, s = c & 1;
                uint4 wv = ring[i % 6];
                if (i + 6 < 40 - ATT_RES)
                    ring[i % 6] = wall[(size_t)(c + 6) * 608 + tid];
                float4 h0 = *(const float4*)&hs[hb + 8 * cs];
                float4 h1 = *(const float4*)&hs[hb + 8 * cs + 4];
                if (s == 0) dot8(wv, h0, h1, a0);
                else dot8(wv, h0, h1, a1);
            }
            pds[(0 * 2 + p) * 304 + m] = a0;
            pds[(1 * 2 + p) * 304 + m] = a1;
        }
        __syncthreads();
        if (tid < 300) {
            float dr = pds[tid] + pds[304 + tid] + bur;
            float dw = pds[608 + tid] + pds[912 + tid] + bu;
            float r = sigm(xr + dr);
            float ht = tanhf(xw + r * dw);
            hs[tid] = gt * ht + (1.f - gt) * hs[tid];
        }
        __syncthreads();
    }
    if (tid < 300)
        hbuf[((size_t)d * NQ + q) * 300 + tid] = hs[tid];
}

__global__ void k_qupd(float* __restrict__ query, const float* __restrict__ hbuf)
{
    int q = blockIdx.x;
    for (int e = threadIdx.x; e < 300; e += blockDim.x)
        query[(size_t)q * 300 + e] += hbuf[(size_t)q * 300 + e]
                                    + hbuf[(size_t)(NQ + q) * 300 + e];
}

// ---------------------------------------------------------------------------
__global__ __launch_bounds__(64)
void k_cls(const float* __restrict__ u, const float* __restrict__ query,
           const float* __restrict__ cw, const float* __restrict__ cb,
           float* __restrict__ out)
{
    int n = blockIdx.x;
    const float* srow = (n == 0) ? u : (query + (size_t)(n - 1) * 300);
    int c = threadIdx.x & 7;
    int part = threadIdx.x >> 3;
    float p = 0.f;
    if (c < NCLS) {
        for (int e = part; e < 300; e += 8) p = fmaf(srow[e], cw[c * 300 + e], p);
    }
    p += __shfl_xor(p, 8);
    p += __shfl_xor(p, 16);
    p += __shfl_xor(p, 32);
    if (part == 0 && c < NCLS) out[n * NCLS + c] = p + cb[c];
}

// ---------------------------------------------------------------------------
extern "C" void kernel_launch(void* const* d_in, const int* in_sizes, int n_in,
                              void* d_out, int out_size, void* d_ws, size_t ws_size,
                              hipStream_t stream)
{
    const int* ids  = (const int*)d_in[0];
    const int* lens = (const int*)d_in[1];
    const float* emb   = (const float*)d_in[2];
    const float* uWih  = (const float*)d_in[3];
    const float* uWhh  = (const float*)d_in[4];
    const float* ubih  = (const float*)d_in[5];
    const float* ubhh  = (const float*)d_in[6];
    const float* linw  = (const float*)d_in[7];
    const float* linb  = (const float*)d_in[8];
    const float* cWih  = (const float*)d_in[9];
    const float* cWhh  = (const float*)d_in[10];
    const float* cbih  = (const float*)d_in[11];
    const float* cbhh  = (const float*)d_in[12];
    const float* aWr_w = (const float*)d_in[13];
    const float* aWr_b = (const float*)d_in[14];
    const float* aUr_w = (const float*)d_in[15];
    const float* aUr_b = (const float*)d_in[16];
    const float* aW_w  = (const float*)d_in[17];
    const float* aW_b  = (const float*)d_in[18];
    const float* aU_w  = (const float*)d_in[19];
    const float* aU_b  = (const float*)d_in[20];
    const float* clsw  = (const float*)d_in[21];
    const float* clsb  = (const float*)d_in[22];
    float* out = (float*)d_out;
    (void)in_sizes; (void)n_in; (void)out_size; (void)ws_size;

    // opt-in to >64KB dynamic LDS (validated working in R6/R7)
    (void)hipFuncSetAttribute((const void*)k_utt_scan,
            hipFuncAttributeMaxDynamicSharedMemorySize, (int)GRU_LDS);
    (void)hipFuncSetAttribute((const void*)k_ctx_scan,
            hipFuncAttributeMaxDynamicSharedMemorySize, (int)GRU_LDS);
    (void)hipFuncSetAttribute((const void*)k_att_scan,
            hipFuncAttributeMaxDynamicSharedMemorySize, (int)ATT_LDS);

    char* base = (char*)d_ws;
    size_t off = 0;
    auto alloc = [&](size_t b) -> void* {
        void* r = (void*)(base + off);
        off += (b + 255) & ~(size_t)255;
        return r;
    };
    short* A_utt  = (short*)alloc((size_t)8192 * KP * 2);          //  5.2 MB
    float* giU    = (float*)alloc((size_t)8192 * 1800 * 4);        // 59.0 MB (reused: xgr)
    float* giC    = (float*)alloc((size_t)5080 * 1800 * 4);        // 36.6 MB (reused: xgw)
    short* wUihB  = (short*)alloc((size_t)1800 * KP * 2);
    short* wCihB  = (short*)alloc((size_t)1800 * KP * 2);
    short* wArB   = (short*)alloc((size_t)1800 * KP * 2);
    short* wAwB   = (short*)alloc((size_t)1800 * KP * 2);
    short* wPackU = (short*)alloc((size_t)2 * 39 * 912 * 8 * 2);   // 1.14 MB
    short* wPackC = (short*)alloc((size_t)2 * 39 * 912 * 8 * 2);
    short* wPackA = (short*)alloc((size_t)6 * 40 * 608 * 8 * 2);   // 2.33 MB
    short* Actx   = (short*)alloc((size_t)5080 * KP * 2);
    float* hout   = (float*)alloc((size_t)2 * NQ * KEFF * 300 * 4);
    float* membank= (float*)alloc((size_t)NQ * KEFF * 300 * 4);
    short* mrkq   = (short*)alloc((size_t)5080 * KP * 2);
    float* mpool  = (float*)alloc((size_t)NN * 600 * 4);
    float* uu     = (float*)alloc((size_t)NN * 300 * 4);
    float* query  = (float*)alloc((size_t)NQ * 300 * 4);
    float* hbuf   = (float*)alloc((size_t)2 * NQ * 300 * 4);
    float* xgr = giU;   // giU dead after k_utt_scan
    float* xgw = giC;   // giC dead after k_ctx_scan

    const int RKQ = NQ * KEFF;  // 5080

    // 0) weight conversions / packing (fused launches)
    k_conv4<<<dim3(1800, 4), dim3(320), 0, stream>>>(uWih, cWih, aWr_w, aW_w,
                                                     wUihB, wCihB, wArB, wAwB);
    k_pack_gru2<<<dim3((2 * 39 * 900 + 255) / 256, 2), dim3(256), 0, stream>>>(
        uWhh, cWhh, wPackU, wPackC);
    k_pack_att<<<dim3((6 * 40 * 600 + 255) / 256), dim3(256), 0, stream>>>(aUr_w, aU_w, wPackA);

    // 1) gather, 2) utt input-gate GEMM (MFMA), 3) utt scan + maxpool
    k_gather_bf16<<<dim3(LL * NN), dim3(320), 0, stream>>>(emb, ids, A_utt);
    k_mgemm<<<dim3(15, 64), dim3(256), 0, stream>>>(A_utt, wUihB, ubih, giU, 8192, 1800);
    k_utt_scan<<<dim3(NN, 2), dim3(960), GRU_LDS, stream>>>(wPackU, ubhh, giU, lens, mpool);
    // 4) u = tanh(maxpool @ lin_w.T + lin_b)
    k_gemm<<<dim3(3, 1), dim3(256), 0, stream>>>(mpool, linw, linb, uu, NN, 300, 600, 1);
    // 5) ctx rows (+ query init fused)
    k_build_ctxA<<<dim3(RKQ), dim3(320), 0, stream>>>(uu, Actx, query);
    // 6) ctx input-gate GEMM + ctx scan + combine
    k_mgemm<<<dim3(15, 40), dim3(256), 0, stream>>>(Actx, wCihB, cbih, giC, RKQ, 1800);
    k_ctx_scan<<<dim3(NQ, 2), dim3(960), GRU_LDS, stream>>>(wPackC, cbhh, giC, hout);
    k_combine<<<dim3(RKQ), dim3(320), 0, stream>>>(uu, hout, membank, mrkq);
    // 7) attention x-projections (all hops/dirs)
    k_mgemm<<<dim3(15, 40), dim3(256), 0, stream>>>(mrkq, wArB, aWr_b, xgr, RKQ, 1800);
    k_mgemm<<<dim3(15, 40), dim3(256), 0, stream>>>(mrkq, wAwB, aW_b, xgw, RKQ, 1800);
    // 8) hops (scores fused into att_scan)
    for (int hop = 0; hop < 3; ++hop) {
        k_att_scan<<<dim3(NQ, 2), dim3(640), ATT_LDS, stream>>>(
            wPackA, aUr_b, aU_b, xgr, xgw, query, membank, hbuf, hop);
        k_qupd<<<dim3(NQ), dim3(128), 0, stream>>>(query, hbuf);
    }
    // 9) classifier
    k_cls<<<dim3(NN), dim3(64), 0, stream>>>(uu, query, clsw, clsb, out);
}